// Round 1
// baseline (274.452 us; speedup 1.0000x reference)
//
#include <hip/hip_runtime.h>
#include <hip/hip_bf16.h>

constexpr int B_ = 4, N_ = 2048, NFEAT = 512, NHID = 64, NHEADS = 4, NCLASS = 64;
constexpr int MAXDEG = 128;
#define LRELU_ALPHA 0.2f

// ---------------------------------------------------------------------------
// Kernel 1: build neighbor lists from dense binary adj. One block per row n.
// Wave-ballot compaction into nbr[n][*]; deg[n] written once (no memset need).
// ---------------------------------------------------------------------------
__global__ __launch_bounds__(256) void build_adj_kernel(
    const float* __restrict__ adj, int* __restrict__ nbr, int* __restrict__ deg) {
  int n = blockIdx.x;
  int tid = threadIdx.x;
  __shared__ int cnt;
  if (tid == 0) cnt = 0;
  __syncthreads();
  for (int m = tid; m < N_; m += 256) {
    bool nz = adj[(size_t)n * N_ + m] != 0.0f;
    unsigned long long mask = __ballot(nz);
    int lane = tid & 63;
    int num = __popcll(mask);
    if (num) {               // wave-uniform
      int base = 0;
      if (lane == 0) base = atomicAdd(&cnt, num);
      base = __shfl(base, 0);
      if (nz) {
        int pos = base + __popcll(mask & ((1ull << lane) - 1ull));
        if (pos < MAXDEG) nbr[n * MAXDEG + pos] = m;
      }
    }
  }
  __syncthreads();
  if (tid == 0) deg[n] = cnt < MAXDEG ? cnt : MAXDEG;
}

// ---------------------------------------------------------------------------
// Tiled fp32 GEMM: Y[rows x 64] = X[rows x K] @ W[K x 64]  (per-head option)
// Block: 256 threads, 32-row tile. K consumed in 64-wide LDS chunks.
// Each thread: one output column d, 8 rows (register-blocked).
// xs[r][f] is wave-uniform (broadcast, free); ws[f][d] is 2-way bank (free).
// ---------------------------------------------------------------------------
template <int K, bool MULTIHEAD>
__global__ __launch_bounds__(256) void gemm_kernel(
    const float* __restrict__ X, const float* __restrict__ W, float* __restrict__ Y) {
  __shared__ float xs[32][64];
  __shared__ float ws[64][64];
  int tid = threadIdx.x;
  int d = tid & 63;
  int w = tid >> 6;                 // wave index = row-group 0..3
  int gr0 = blockIdx.x * 32;        // global row base (rows are flat over B*N)
  const float* Xb = X + (size_t)gr0 * K;
  const float* Wb = W + (size_t)blockIdx.y * K * 64;
  float acc[8] = {0.f, 0.f, 0.f, 0.f, 0.f, 0.f, 0.f, 0.f};

  for (int fc = 0; fc < K; fc += 64) {
    // stage X tile: 32x64 floats, 8 per thread (2x float4)
    {
      int idx = tid * 8;
      int xr = idx >> 6, xc = idx & 63;
      const float* src = Xb + (size_t)xr * K + fc + xc;
      *(float4*)&xs[xr][xc]     = *(const float4*)(src);
      *(float4*)&xs[xr][xc + 4] = *(const float4*)(src + 4);
    }
    // stage W tile: 64x64 floats, 16 per thread (4x float4)
    {
      int wr = tid >> 2, wc = (tid & 3) * 16;
      const float* src = Wb + (size_t)(fc + wr) * 64 + wc;
      *(float4*)&ws[wr][wc]      = *(const float4*)(src);
      *(float4*)&ws[wr][wc + 4]  = *(const float4*)(src + 4);
      *(float4*)&ws[wr][wc + 8]  = *(const float4*)(src + 8);
      *(float4*)&ws[wr][wc + 12] = *(const float4*)(src + 12);
    }
    __syncthreads();
#pragma unroll 8
    for (int f = 0; f < 64; ++f) {
      float wv = ws[f][d];
#pragma unroll
      for (int p = 0; p < 8; ++p)
        acc[p] = fmaf(xs[w + p * 4][f], wv, acc[p]);
    }
    __syncthreads();
  }

#pragma unroll
  for (int p = 0; p < 8; ++p) {
    int gr = gr0 + w + p * 4;
    size_t oidx;
    if (MULTIHEAD) {
      int b = gr >> 11;            // N_ = 2048
      int n = gr & (N_ - 1);
      oidx = (((size_t)(b * NHEADS + blockIdx.y)) * N_ + n) * 64 + d;
    } else {
      oidx = (size_t)gr * 64 + d;
    }
    Y[oidx] = acc[p];
  }
}

// ---------------------------------------------------------------------------
// Row dots: s_src[row] = <H[row,:], a[h,0:64]>, s_dst = <H[row,:], a[h,64:128]>
// One wave per row, butterfly shuffle reduce.
// ---------------------------------------------------------------------------
template <int NH>
__global__ __launch_bounds__(256) void rowdot_kernel(
    const float* __restrict__ Hm, const float* __restrict__ a,
    float* __restrict__ ssrc, float* __restrict__ sdst) {
  int w = threadIdx.x >> 6, lane = threadIdx.x & 63;
  int gr = blockIdx.x * 4 + w;
  int hh = (NH > 1) ? ((gr >> 11) & (NH - 1)) : 0;
  float v = Hm[(size_t)gr * 64 + lane];
  float s1 = v * a[hh * 128 + lane];
  float s2 = v * a[hh * 128 + 64 + lane];
#pragma unroll
  for (int off = 32; off; off >>= 1) {
    s1 += __shfl_xor(s1, off);
    s2 += __shfl_xor(s2, off);
  }
  if (lane == 0) { ssrc[gr] = s1; sdst[gr] = s2; }
}

// ---------------------------------------------------------------------------
// Layer-1 sparse attention aggregation + ELU + head concat.
// One wave per (b,h,n); lane = output dim d.
// ---------------------------------------------------------------------------
__global__ __launch_bounds__(256) void attn1_kernel(
    const float* __restrict__ Hm, const float* __restrict__ ssrc,
    const float* __restrict__ sdst, const int* __restrict__ nbr,
    const int* __restrict__ deg, float* __restrict__ h1) {
  int w = threadIdx.x >> 6, lane = threadIdx.x & 63;
  int gr = blockIdx.x * 4 + w;        // 0..B*H*N
  int n = gr & (N_ - 1);
  int bh = gr >> 11;
  float ss = ssrc[gr];
  int dg = deg[n];
  const int* nb = nbr + n * MAXDEG;
  const float* hb = Hm + (size_t)bh * N_ * 64;
  const float* sdb = sdst + (size_t)bh * N_;
  float acc = 0.f, den = 0.f;
  for (int k = 0; k < dg; ++k) {
    int m = nb[k];
    float sv = ss + sdb[m];
    float lr = sv > 0.f ? sv : LRELU_ALPHA * sv;
    float ev = __expf(-lr);
    den += ev;
    acc = fmaf(ev, hb[(size_t)m * 64 + lane], acc);
  }
  float o = acc / den;
  o = o > 0.f ? o : expm1f(o);
  int b = bh >> 2, hh = bh & 3;
  h1[((size_t)b * N_ + n) * (NHEADS * NHID) + hh * 64 + lane] = o;
}

// ---------------------------------------------------------------------------
// Layer-2 sparse attention aggregation + final ELU -> d_out.
// One wave per (b,n).
// ---------------------------------------------------------------------------
__global__ __launch_bounds__(256) void attn2_kernel(
    const float* __restrict__ G, const float* __restrict__ tsrc,
    const float* __restrict__ tdst, const int* __restrict__ nbr,
    const int* __restrict__ deg, float* __restrict__ out) {
  int w = threadIdx.x >> 6, lane = threadIdx.x & 63;
  int gr = blockIdx.x * 4 + w;        // 0..B*N
  int n = gr & (N_ - 1);
  int b = gr >> 11;
  float ss = tsrc[gr];
  int dg = deg[n];
  const int* nb = nbr + n * MAXDEG;
  const float* gb = G + (size_t)b * N_ * 64;
  const float* sdb = tdst + (size_t)b * N_;
  float acc = 0.f, den = 0.f;
  for (int k = 0; k < dg; ++k) {
    int m = nb[k];
    float sv = ss + sdb[m];
    float lr = sv > 0.f ? sv : LRELU_ALPHA * sv;
    float ev = __expf(-lr);
    den += ev;
    acc = fmaf(ev, gb[(size_t)m * 64 + lane], acc);
  }
  float o = acc / den;
  out[(size_t)gr * 64 + lane] = o > 0.f ? o : expm1f(o);
}

// ---------------------------------------------------------------------------
extern "C" void kernel_launch(void* const* d_in, const int* in_sizes, int n_in,
                              void* d_out, int out_size, void* d_ws, size_t ws_size,
                              hipStream_t stream) {
  const float* x   = (const float*)d_in[0];   // [B,N,512]
  const float* adj = (const float*)d_in[1];   // [N,N]
  const float* W1  = (const float*)d_in[2];   // [H,512,64]
  const float* a1  = (const float*)d_in[3];   // [H,128]
  const float* W2  = (const float*)d_in[4];   // [256,64]
  const float* a2  = (const float*)d_in[5];   // [128]
  float* out = (float*)d_out;                 // [B,N,64] fp32

  char* ws = (char*)d_ws;
  float* h    = (float*)ws; ws += (size_t)B_ * NHEADS * N_ * 64 * 4;  // 8 MB  [B,H,N,64]
  float* h1   = (float*)ws; ws += (size_t)B_ * N_ * 256 * 4;          // 8 MB  [B,N,256]
  float* g    = (float*)ws; ws += (size_t)B_ * N_ * 64 * 4;           // 2 MB  [B,N,64]
  float* ssrc = (float*)ws; ws += (size_t)B_ * NHEADS * N_ * 4;
  float* sdst = (float*)ws; ws += (size_t)B_ * NHEADS * N_ * 4;
  float* tsrc = (float*)ws; ws += (size_t)B_ * N_ * 4;
  float* tdst = (float*)ws; ws += (size_t)B_ * N_ * 4;
  int*   nbr  = (int*)ws;   ws += (size_t)N_ * MAXDEG * 4;            // 1 MB
  int*   deg  = (int*)ws;   ws += (size_t)N_ * 4;

  build_adj_kernel<<<N_, 256, 0, stream>>>(adj, nbr, deg);
  gemm_kernel<NFEAT, true><<<dim3(B_ * N_ / 32, NHEADS), 256, 0, stream>>>(x, W1, h);
  rowdot_kernel<NHEADS><<<B_ * NHEADS * N_ / 4, 256, 0, stream>>>(h, a1, ssrc, sdst);
  attn1_kernel<<<B_ * NHEADS * N_ / 4, 256, 0, stream>>>(h, ssrc, sdst, nbr, deg, h1);
  gemm_kernel<NHEADS * NHID, false><<<dim3(B_ * N_ / 32, 1), 256, 0, stream>>>(h1, W2, g);
  rowdot_kernel<1><<<B_ * N_ / 4, 256, 0, stream>>>(g, a2, tsrc, tdst);
  attn2_kernel<<<B_ * N_ / 4, 256, 0, stream>>>(g, tsrc, tdst, nbr, deg, out);
}

// Round 2
// 207.514 us; speedup vs baseline: 1.3226x; 1.3226x over previous
//
#include <hip/hip_runtime.h>
#include <hip/hip_bf16.h>

constexpr int B_ = 4, N_ = 2048, NFEAT = 512, NHID = 64, NHEADS = 4, NCLASS = 64;
constexpr int MAXDEG = 128;
#define LRELU_ALPHA 0.2f

// ---------------------------------------------------------------------------
// Kernel 1: build neighbor lists from dense binary adj. One block per row n.
// ---------------------------------------------------------------------------
__global__ __launch_bounds__(256) void build_adj_kernel(
    const float* __restrict__ adj, int* __restrict__ nbr, int* __restrict__ deg) {
  int n = blockIdx.x;
  int tid = threadIdx.x;
  __shared__ int cnt;
  if (tid == 0) cnt = 0;
  __syncthreads();
  for (int m = tid; m < N_; m += 256) {
    bool nz = adj[(size_t)n * N_ + m] != 0.0f;
    unsigned long long mask = __ballot(nz);
    int lane = tid & 63;
    int num = __popcll(mask);
    if (num) {               // wave-uniform
      int base = 0;
      if (lane == 0) base = atomicAdd(&cnt, num);
      base = __shfl(base, 0);
      if (nz) {
        int pos = base + __popcll(mask & ((1ull << lane) - 1ull));
        if (pos < MAXDEG) nbr[n * MAXDEG + pos] = m;
      }
    }
  }
  __syncthreads();
  if (tid == 0) deg[n] = cnt < MAXDEG ? cnt : MAXDEG;
}

// ---------------------------------------------------------------------------
// Tiled fp32 GEMM: Y[rows x 64] = X[rows x K] @ W[K x 64]
// ---------------------------------------------------------------------------
template <int K, bool MULTIHEAD>
__global__ __launch_bounds__(256) void gemm_kernel(
    const float* __restrict__ X, const float* __restrict__ W, float* __restrict__ Y) {
  __shared__ float xs[32][64];
  __shared__ float ws[64][64];
  int tid = threadIdx.x;
  int d = tid & 63;
  int w = tid >> 6;                 // wave index = row-group 0..3
  int gr0 = blockIdx.x * 32;        // global row base (rows are flat over B*N)
  const float* Xb = X + (size_t)gr0 * K;
  const float* Wb = W + (size_t)blockIdx.y * K * 64;
  float acc[8] = {0.f, 0.f, 0.f, 0.f, 0.f, 0.f, 0.f, 0.f};

  for (int fc = 0; fc < K; fc += 64) {
    {
      int idx = tid * 8;
      int xr = idx >> 6, xc = idx & 63;
      const float* src = Xb + (size_t)xr * K + fc + xc;
      *(float4*)&xs[xr][xc]     = *(const float4*)(src);
      *(float4*)&xs[xr][xc + 4] = *(const float4*)(src + 4);
    }
    {
      int wr = tid >> 2, wc = (tid & 3) * 16;
      const float* src = Wb + (size_t)(fc + wr) * 64 + wc;
      *(float4*)&ws[wr][wc]      = *(const float4*)(src);
      *(float4*)&ws[wr][wc + 4]  = *(const float4*)(src + 4);
      *(float4*)&ws[wr][wc + 8]  = *(const float4*)(src + 8);
      *(float4*)&ws[wr][wc + 12] = *(const float4*)(src + 12);
    }
    __syncthreads();
#pragma unroll 8
    for (int f = 0; f < 64; ++f) {
      float wv = ws[f][d];
#pragma unroll
      for (int p = 0; p < 8; ++p)
        acc[p] = fmaf(xs[w + p * 4][f], wv, acc[p]);
    }
    __syncthreads();
  }

#pragma unroll
  for (int p = 0; p < 8; ++p) {
    int gr = gr0 + w + p * 4;
    size_t oidx;
    if (MULTIHEAD) {
      int b = gr >> 11;            // N_ = 2048
      int n = gr & (N_ - 1);
      oidx = (((size_t)(b * NHEADS + blockIdx.y)) * N_ + n) * 64 + d;
    } else {
      oidx = (size_t)gr * 64 + d;
    }
    Y[oidx] = acc[p];
  }
}

// ---------------------------------------------------------------------------
// Row dots: one wave per row, butterfly shuffle reduce.
// ---------------------------------------------------------------------------
template <int NH>
__global__ __launch_bounds__(256) void rowdot_kernel(
    const float* __restrict__ Hm, const float* __restrict__ a,
    float* __restrict__ ssrc, float* __restrict__ sdst) {
  int w = threadIdx.x >> 6, lane = threadIdx.x & 63;
  int gr = blockIdx.x * 4 + w;
  int hh = (NH > 1) ? ((gr >> 11) & (NH - 1)) : 0;
  float v = Hm[(size_t)gr * 64 + lane];
  float s1 = v * a[hh * 128 + lane];
  float s2 = v * a[hh * 128 + 64 + lane];
#pragma unroll
  for (int off = 32; off; off >>= 1) {
    s1 += __shfl_xor(s1, off);
    s2 += __shfl_xor(s2, off);
  }
  if (lane == 0) { ssrc[gr] = s1; sdst[gr] = s2; }
}

// ---------------------------------------------------------------------------
// Sparse attention aggregation, 8-wide software-pipelined neighbor loop.
// plane = per-(b[,h]) base of the feature matrix; sdb = per-(b[,h]) dst scores.
// Returns num/den with ILP-8 load batching (8 outstanding VMEM ops).
// ---------------------------------------------------------------------------
__device__ __forceinline__ float sparse_agg(
    const float* __restrict__ plane, const float* __restrict__ sdb,
    const int* __restrict__ nb, int dg, float ss, int lane) {
  float acc0 = 0.f, acc1 = 0.f, den0 = 0.f, den1 = 0.f;
  int k = 0;
  for (; k + 8 <= dg; k += 8) {
    int m[8];
    float sv[8], hv[8];
#pragma unroll
    for (int j = 0; j < 8; ++j) m[j] = nb[k + j];
#pragma unroll
    for (int j = 0; j < 8; ++j) sv[j] = sdb[m[j]];
#pragma unroll
    for (int j = 0; j < 8; ++j) hv[j] = plane[(size_t)m[j] * 64 + lane];
#pragma unroll
    for (int j = 0; j < 8; ++j) {
      float s = ss + sv[j];
      float lr = s > 0.f ? s : LRELU_ALPHA * s;
      float ev = __expf(-lr);
      if (j & 1) { den1 += ev; acc1 = fmaf(ev, hv[j], acc1); }
      else       { den0 += ev; acc0 = fmaf(ev, hv[j], acc0); }
    }
  }
  for (; k < dg; ++k) {
    int m = nb[k];
    float s = ss + sdb[m];
    float lr = s > 0.f ? s : LRELU_ALPHA * s;
    float ev = __expf(-lr);
    den0 += ev;
    acc0 = fmaf(ev, plane[(size_t)m * 64 + lane], acc0);
  }
  return (acc0 + acc1) / (den0 + den1);
}

// ---------------------------------------------------------------------------
// Layer-1 sparse attention aggregation + ELU + head concat. One wave/(b,h,n).
// ---------------------------------------------------------------------------
__global__ __launch_bounds__(256) void attn1_kernel(
    const float* __restrict__ Hm, const float* __restrict__ ssrc,
    const float* __restrict__ sdst, const int* __restrict__ nbr,
    const int* __restrict__ deg, float* __restrict__ h1) {
  int w = threadIdx.x >> 6, lane = threadIdx.x & 63;
  int gr = blockIdx.x * 4 + w;        // 0..B*H*N
  int n = gr & (N_ - 1);
  int bh = gr >> 11;
  float o = sparse_agg(Hm + (size_t)bh * N_ * 64, sdst + (size_t)bh * N_,
                       nbr + n * MAXDEG, deg[n], ssrc[gr], lane);
  o = o > 0.f ? o : expm1f(o);
  int b = bh >> 2, hh = bh & 3;
  h1[((size_t)b * N_ + n) * (NHEADS * NHID) + hh * 64 + lane] = o;
}

// ---------------------------------------------------------------------------
// Layer-2 sparse attention aggregation + final ELU -> d_out. One wave/(b,n).
// ---------------------------------------------------------------------------
__global__ __launch_bounds__(256) void attn2_kernel(
    const float* __restrict__ G, const float* __restrict__ tsrc,
    const float* __restrict__ tdst, const int* __restrict__ nbr,
    const int* __restrict__ deg, float* __restrict__ out) {
  int w = threadIdx.x >> 6, lane = threadIdx.x & 63;
  int gr = blockIdx.x * 4 + w;        // 0..B*N
  int n = gr & (N_ - 1);
  int b = gr >> 11;
  float o = sparse_agg(G + (size_t)b * N_ * 64, tdst + (size_t)b * N_,
                       nbr + n * MAXDEG, deg[n], tsrc[gr], lane);
  out[(size_t)gr * 64 + lane] = o > 0.f ? o : expm1f(o);
}

// ---------------------------------------------------------------------------
extern "C" void kernel_launch(void* const* d_in, const int* in_sizes, int n_in,
                              void* d_out, int out_size, void* d_ws, size_t ws_size,
                              hipStream_t stream) {
  const float* x   = (const float*)d_in[0];   // [B,N,512]
  const float* adj = (const float*)d_in[1];   // [N,N]
  const float* W1  = (const float*)d_in[2];   // [H,512,64]
  const float* a1  = (const float*)d_in[3];   // [H,128]
  const float* W2  = (const float*)d_in[4];   // [256,64]
  const float* a2  = (const float*)d_in[5];   // [128]
  float* out = (float*)d_out;                 // [B,N,64] fp32

  char* ws = (char*)d_ws;
  float* h    = (float*)ws; ws += (size_t)B_ * NHEADS * N_ * 64 * 4;  // 8 MB  [B,H,N,64]
  float* h1   = (float*)ws; ws += (size_t)B_ * N_ * 256 * 4;          // 8 MB  [B,N,256]
  float* g    = (float*)ws; ws += (size_t)B_ * N_ * 64 * 4;           // 2 MB  [B,N,64]
  float* ssrc = (float*)ws; ws += (size_t)B_ * NHEADS * N_ * 4;
  float* sdst = (float*)ws; ws += (size_t)B_ * NHEADS * N_ * 4;
  float* tsrc = (float*)ws; ws += (size_t)B_ * N_ * 4;
  float* tdst = (float*)ws; ws += (size_t)B_ * N_ * 4;
  int*   nbr  = (int*)ws;   ws += (size_t)N_ * MAXDEG * 4;            // 1 MB
  int*   deg  = (int*)ws;   ws += (size_t)N_ * 4;

  build_adj_kernel<<<N_, 256, 0, stream>>>(adj, nbr, deg);
  gemm_kernel<NFEAT, true><<<dim3(B_ * N_ / 32, NHEADS), 256, 0, stream>>>(x, W1, h);
  rowdot_kernel<NHEADS><<<B_ * NHEADS * N_ / 4, 256, 0, stream>>>(h, a1, ssrc, sdst);
  attn1_kernel<<<B_ * NHEADS * N_ / 4, 256, 0, stream>>>(h, ssrc, sdst, nbr, deg, h1);
  gemm_kernel<NHEADS * NHID, false><<<dim3(B_ * N_ / 32, 1), 256, 0, stream>>>(h1, W2, g);
  rowdot_kernel<1><<<B_ * N_ / 4, 256, 0, stream>>>(g, a2, tsrc, tdst);
  attn2_kernel<<<B_ * N_ / 4, 256, 0, stream>>>(g, tsrc, tdst, nbr, deg, out);
}

// Round 4
// 180.353 us; speedup vs baseline: 1.5217x; 1.1506x over previous
//
#include <hip/hip_runtime.h>
#include <hip/hip_bf16.h>

constexpr int B_ = 4, N_ = 2048, NFEAT = 512, NHID = 64, NHEADS = 4, NCLASS = 64;
constexpr int MAXDEG = 128;
#define LRELU_ALPHA 0.2f

// ---------------------------------------------------------------------------
// Kernel 1: build neighbor lists from dense binary adj. One block per row n.
// ---------------------------------------------------------------------------
__global__ __launch_bounds__(256) void build_adj_kernel(
    const float* __restrict__ adj, int* __restrict__ nbr, int* __restrict__ deg) {
  int n = blockIdx.x;
  int tid = threadIdx.x;
  __shared__ int cnt;
  if (tid == 0) cnt = 0;
  __syncthreads();
  for (int m = tid; m < N_; m += 256) {
    bool nz = adj[(size_t)n * N_ + m] != 0.0f;
    unsigned long long mask = __ballot(nz);
    int lane = tid & 63;
    int num = __popcll(mask);
    if (num) {               // wave-uniform
      int base = 0;
      if (lane == 0) base = atomicAdd(&cnt, num);
      base = __shfl(base, 0);
      if (nz) {
        int pos = base + __popcll(mask & ((1ull << lane) - 1ull));
        if (pos < MAXDEG) nbr[n * MAXDEG + pos] = m;
      }
    }
  }
  __syncthreads();
  if (tid == 0) deg[n] = cnt < MAXDEG ? cnt : MAXDEG;
}

// ---------------------------------------------------------------------------
// Register-tiled fp32 GEMM: Y[rows x 64] = X[rows x K] @ W[K x 64]
// Block tile 64 rows x 64 cols, 256 threads, each 4 rows x 4 cols (16 acc).
// X tile stored TRANSPOSED in LDS (xs_t[f][row], stride 68: 16B-aligned pad)
// so inner body per f = 2x ds_read_b128 + 16 FMA (VALU-bound).
// ---------------------------------------------------------------------------
template <int K, bool MULTIHEAD>
__global__ __launch_bounds__(256) void gemm_kernel(
    const float* __restrict__ X, const float* __restrict__ W, float* __restrict__ Y) {
  __shared__ float xs_t[64][68];   // [f][row]
  __shared__ float ws[64][68];     // [f][col]
  int tid = threadIdx.x;
  int tc4 = (tid & 15) * 4;        // col base
  int tr4 = (tid >> 4) * 4;        // row base
  int row0 = blockIdx.x * 64;      // global row base (rows flat over B*N)
  const float* Xb = X + (size_t)row0 * K;
  const float* Wb = W + (size_t)blockIdx.y * K * 64;

  int sr = tid >> 2;               // staging row/f index 0..63
  int sc = (tid & 3) * 16;         // staging col base {0,16,32,48}

  float4 acc[4];
#pragma unroll
  for (int i = 0; i < 4; ++i) acc[i] = make_float4(0.f, 0.f, 0.f, 0.f);

  for (int fc = 0; fc < K; fc += 64) {
    // stage X tile transposed: thread loads X[sr][fc+sc .. +15], scatters.
    {
      const float* src = Xb + (size_t)sr * K + fc + sc;
      float v[16];
      *(float4*)&v[0]  = ((const float4*)src)[0];
      *(float4*)&v[4]  = ((const float4*)src)[1];
      *(float4*)&v[8]  = ((const float4*)src)[2];
      *(float4*)&v[12] = ((const float4*)src)[3];
#pragma unroll
      for (int j = 0; j < 16; ++j) xs_t[sc + j][sr] = v[j];
    }
    // stage W tile: thread copies W[fc+sr][sc .. +15] straight in.
    {
      const float* src = Wb + (size_t)(fc + sr) * 64 + sc;
      *(float4*)&ws[sr][sc]      = ((const float4*)src)[0];
      *(float4*)&ws[sr][sc + 4]  = ((const float4*)src)[1];
      *(float4*)&ws[sr][sc + 8]  = ((const float4*)src)[2];
      *(float4*)&ws[sr][sc + 12] = ((const float4*)src)[3];
    }
    __syncthreads();
#pragma unroll 8
    for (int f = 0; f < 64; ++f) {
      float4 xv = *(const float4*)&xs_t[f][tr4];
      float4 wv = *(const float4*)&ws[f][tc4];
      acc[0].x = fmaf(xv.x, wv.x, acc[0].x);
      acc[0].y = fmaf(xv.x, wv.y, acc[0].y);
      acc[0].z = fmaf(xv.x, wv.z, acc[0].z);
      acc[0].w = fmaf(xv.x, wv.w, acc[0].w);
      acc[1].x = fmaf(xv.y, wv.x, acc[1].x);
      acc[1].y = fmaf(xv.y, wv.y, acc[1].y);
      acc[1].z = fmaf(xv.y, wv.z, acc[1].z);
      acc[1].w = fmaf(xv.y, wv.w, acc[1].w);
      acc[2].x = fmaf(xv.z, wv.x, acc[2].x);
      acc[2].y = fmaf(xv.z, wv.y, acc[2].y);
      acc[2].z = fmaf(xv.z, wv.z, acc[2].z);
      acc[2].w = fmaf(xv.z, wv.w, acc[2].w);
      acc[3].x = fmaf(xv.w, wv.x, acc[3].x);
      acc[3].y = fmaf(xv.w, wv.y, acc[3].y);
      acc[3].z = fmaf(xv.w, wv.z, acc[3].z);
      acc[3].w = fmaf(xv.w, wv.w, acc[3].w);
    }
    __syncthreads();
  }

#pragma unroll
  for (int i = 0; i < 4; ++i) {
    int gr = row0 + tr4 + i;
    size_t oidx;
    if (MULTIHEAD) {
      int b = gr >> 11;            // N_ = 2048
      int n = gr & (N_ - 1);
      oidx = (((size_t)(b * NHEADS + blockIdx.y)) * N_ + n) * 64 + tc4;
    } else {
      oidx = (size_t)gr * 64 + tc4;
    }
    *(float4*)&Y[oidx] = acc[i];
  }
}

// ---------------------------------------------------------------------------
// Row dots: one wave per row, butterfly shuffle reduce.
// ---------------------------------------------------------------------------
template <int NH>
__global__ __launch_bounds__(256) void rowdot_kernel(
    const float* __restrict__ Hm, const float* __restrict__ a,
    float* __restrict__ ssrc, float* __restrict__ sdst) {
  int w = threadIdx.x >> 6, lane = threadIdx.x & 63;
  int gr = blockIdx.x * 4 + w;
  int hh = (NH > 1) ? ((gr >> 11) & (NH - 1)) : 0;
  float v = Hm[(size_t)gr * 64 + lane];
  float s1 = v * a[hh * 128 + lane];
  float s2 = v * a[hh * 128 + 64 + lane];
#pragma unroll
  for (int off = 32; off; off >>= 1) {
    s1 += __shfl_xor(s1, off);
    s2 += __shfl_xor(s2, off);
  }
  if (lane == 0) { ssrc[gr] = s1; sdst[gr] = s2; }
}

// ---------------------------------------------------------------------------
// Sparse attention aggregation, 8-wide software-pipelined neighbor loop.
// ---------------------------------------------------------------------------
__device__ __forceinline__ float sparse_agg(
    const float* __restrict__ plane, const float* __restrict__ sdb,
    const int* __restrict__ nb, int dg, float ss, int lane) {
  float acc0 = 0.f, acc1 = 0.f, den0 = 0.f, den1 = 0.f;
  int k = 0;
  for (; k + 8 <= dg; k += 8) {
    int m[8];
    float sv[8], hv[8];
#pragma unroll
    for (int j = 0; j < 8; ++j) m[j] = nb[k + j];
#pragma unroll
    for (int j = 0; j < 8; ++j) sv[j] = sdb[m[j]];
#pragma unroll
    for (int j = 0; j < 8; ++j) hv[j] = plane[(size_t)m[j] * 64 + lane];
#pragma unroll
    for (int j = 0; j < 8; ++j) {
      float s = ss + sv[j];
      float lr = s > 0.f ? s : LRELU_ALPHA * s;
      float ev = __expf(-lr);
      if (j & 1) { den1 += ev; acc1 = fmaf(ev, hv[j], acc1); }
      else       { den0 += ev; acc0 = fmaf(ev, hv[j], acc0); }
    }
  }
  for (; k < dg; ++k) {
    int m = nb[k];
    float s = ss + sdb[m];
    float lr = s > 0.f ? s : LRELU_ALPHA * s;
    float ev = __expf(-lr);
    den0 += ev;
    acc0 = fmaf(ev, plane[(size_t)m * 64 + lane], acc0);
  }
  return (acc0 + acc1) / (den0 + den1);
}

// ---------------------------------------------------------------------------
// Layer-1 sparse attention aggregation + ELU + head concat. One wave/(b,h,n).
// ---------------------------------------------------------------------------
__global__ __launch_bounds__(256) void attn1_kernel(
    const float* __restrict__ Hm, const float* __restrict__ ssrc,
    const float* __restrict__ sdst, const int* __restrict__ nbr,
    const int* __restrict__ deg, float* __restrict__ h1) {
  int w = threadIdx.x >> 6, lane = threadIdx.x & 63;
  int gr = blockIdx.x * 4 + w;        // 0..B*H*N
  int n = gr & (N_ - 1);
  int bh = gr >> 11;
  float o = sparse_agg(Hm + (size_t)bh * N_ * 64, sdst + (size_t)bh * N_,
                       nbr + n * MAXDEG, deg[n], ssrc[gr], lane);
  o = o > 0.f ? o : expm1f(o);
  int b = bh >> 2, hh = bh & 3;
  h1[((size_t)b * N_ + n) * (NHEADS * NHID) + hh * 64 + lane] = o;
}

// ---------------------------------------------------------------------------
// Layer-2 sparse attention aggregation + final ELU -> d_out. One wave/(b,n).
// ---------------------------------------------------------------------------
__global__ __launch_bounds__(256) void attn2_kernel(
    const float* __restrict__ G, const float* __restrict__ tsrc,
    const float* __restrict__ tdst, const int* __restrict__ nbr,
    const int* __restrict__ deg, float* __restrict__ out) {
  int w = threadIdx.x >> 6, lane = threadIdx.x & 63;
  int gr = blockIdx.x * 4 + w;        // 0..B*N
  int n = gr & (N_ - 1);
  int b = gr >> 11;
  float o = sparse_agg(G + (size_t)b * N_ * 64, tdst + (size_t)b * N_,
                       nbr + n * MAXDEG, deg[n], tsrc[gr], lane);
  out[(size_t)gr * 64 + lane] = o > 0.f ? o : expm1f(o);
}

// ---------------------------------------------------------------------------
extern "C" void kernel_launch(void* const* d_in, const int* in_sizes, int n_in,
                              void* d_out, int out_size, void* d_ws, size_t ws_size,
                              hipStream_t stream) {
  const float* x   = (const float*)d_in[0];   // [B,N,512]
  const float* adj = (const float*)d_in[1];   // [N,N]
  const float* W1  = (const float*)d_in[2];   // [H,512,64]
  const float* a1  = (const float*)d_in[3];   // [H,128]
  const float* W2  = (const float*)d_in[4];   // [256,64]
  const float* a2  = (const float*)d_in[5];   // [128]
  float* out = (float*)d_out;                 // [B,N,64] fp32

  char* ws = (char*)d_ws;
  float* h    = (float*)ws; ws += (size_t)B_ * NHEADS * N_ * 64 * 4;  // 8 MB  [B,H,N,64]
  float* h1   = (float*)ws; ws += (size_t)B_ * N_ * 256 * 4;          // 8 MB  [B,N,256]
  float* g    = (float*)ws; ws += (size_t)B_ * N_ * 64 * 4;           // 2 MB  [B,N,64]
  float* ssrc = (float*)ws; ws += (size_t)B_ * NHEADS * N_ * 4;
  float* sdst = (float*)ws; ws += (size_t)B_ * NHEADS * N_ * 4;
  float* tsrc = (float*)ws; ws += (size_t)B_ * N_ * 4;
  float* tdst = (float*)ws; ws += (size_t)B_ * N_ * 4;
  int*   nbr  = (int*)ws;   ws += (size_t)N_ * MAXDEG * 4;            // 1 MB
  int*   deg  = (int*)ws;   ws += (size_t)N_ * 4;

  build_adj_kernel<<<N_, 256, 0, stream>>>(adj, nbr, deg);
  gemm_kernel<NFEAT, true><<<dim3(B_ * N_ / 64, NHEADS), 256, 0, stream>>>(x, W1, h);
  rowdot_kernel<NHEADS><<<B_ * NHEADS * N_ / 4, 256, 0, stream>>>(h, a1, ssrc, sdst);
  attn1_kernel<<<B_ * NHEADS * N_ / 4, 256, 0, stream>>>(h, ssrc, sdst, nbr, deg, h1);
  gemm_kernel<NHEADS * NHID, false><<<dim3(B_ * N_ / 64, 1), 256, 0, stream>>>(h1, W2, g);
  rowdot_kernel<1><<<B_ * N_ / 4, 256, 0, stream>>>(g, a2, tsrc, tdst);
  attn2_kernel<<<B_ * N_ / 4, 256, 0, stream>>>(g, tsrc, tdst, nbr, deg, out);
}

// Round 5
// 167.035 us; speedup vs baseline: 1.6431x; 1.0797x over previous
//
#include <hip/hip_runtime.h>
#include <hip/hip_bf16.h>

constexpr int B_ = 4, N_ = 2048, NFEAT = 512, NHID = 64, NHEADS = 4, NCLASS = 64;
constexpr int MAXDEG = 128;
#define LRELU_ALPHA 0.2f

typedef __attribute__((ext_vector_type(8))) short short8;
typedef __attribute__((ext_vector_type(4))) float f32x4;

__device__ __forceinline__ unsigned short f2bf_rne(float f) {
  unsigned int u = __float_as_uint(f);
  unsigned int r = (u + 0x7FFFu + ((u >> 16) & 1u)) >> 16;
  return (unsigned short)r;
}
__device__ __forceinline__ float bf2f(unsigned short h) {
  return __uint_as_float(((unsigned int)h) << 16);
}

// ---------------------------------------------------------------------------
// Kernel 1: build neighbor lists from dense binary adj. One block per row n.
// ---------------------------------------------------------------------------
__global__ __launch_bounds__(256) void build_adj_kernel(
    const float* __restrict__ adj, int* __restrict__ nbr, int* __restrict__ deg) {
  int n = blockIdx.x;
  int tid = threadIdx.x;
  __shared__ int cnt;
  if (tid == 0) cnt = 0;
  __syncthreads();
  for (int m = tid; m < N_; m += 256) {
    bool nz = adj[(size_t)n * N_ + m] != 0.0f;
    unsigned long long mask = __ballot(nz);
    int lane = tid & 63;
    int num = __popcll(mask);
    if (num) {               // wave-uniform
      int base = 0;
      if (lane == 0) base = atomicAdd(&cnt, num);
      base = __shfl(base, 0);
      if (nz) {
        int pos = base + __popcll(mask & ((1ull << lane) - 1ull));
        if (pos < MAXDEG) nbr[n * MAXDEG + pos] = m;
      }
    }
  }
  __syncthreads();
  if (tid == 0) deg[n] = cnt < MAXDEG ? cnt : MAXDEG;
}

// ---------------------------------------------------------------------------
// prep_x: split x (fp32) into hi/lo bf16 planes, 8 elements/thread.
// ---------------------------------------------------------------------------
__global__ __launch_bounds__(256) void prep_x_kernel(
    const float* __restrict__ x, unsigned short* __restrict__ xhi,
    unsigned short* __restrict__ xlo) {
  size_t idx = ((size_t)blockIdx.x * 256 + threadIdx.x) * 8;
  float4 v0 = *(const float4*)&x[idx];
  float4 v1 = *(const float4*)&x[idx + 4];
  float v[8] = {v0.x, v0.y, v0.z, v0.w, v1.x, v1.y, v1.z, v1.w};
  short8 sh, sl;
#pragma unroll
  for (int j = 0; j < 8; ++j) {
    unsigned short hi = f2bf_rne(v[j]);
    sh[j] = (short)hi;
    sl[j] = (short)f2bf_rne(v[j] - bf2f(hi));
  }
  *(short8*)&xhi[idx] = sh;
  *(short8*)&xlo[idx] = sl;
}

// ---------------------------------------------------------------------------
// prep_w: W1[h][k][n] -> transposed hi/lo bf16  wt*[h][n][k]  (B-fragment layout)
// grid (NFEAT/64, NHEADS), LDS 64x64 tile transpose.
// ---------------------------------------------------------------------------
__global__ __launch_bounds__(256) void prep_w_kernel(
    const float* __restrict__ W1, unsigned short* __restrict__ wth,
    unsigned short* __restrict__ wtl) {
  __shared__ float ts[64][65];
  int h = blockIdx.y, k0 = blockIdx.x * 64;
  int tid = threadIdx.x;
  int kr = tid >> 2, nc = (tid & 3) * 16;
  const float* src = W1 + ((size_t)h * NFEAT + k0 + kr) * 64 + nc;
#pragma unroll
  for (int j = 0; j < 4; ++j)
    *(float4*)&ts[kr][nc + 4 * j] = *(const float4*)(src + 4 * j);
  __syncthreads();
  int n = tid >> 2, kc = (tid & 3) * 16;
  short8 h0, h1v, l0, l1v;
#pragma unroll
  for (int j = 0; j < 8; ++j) {
    float a = ts[kc + j][n];
    float b = ts[kc + 8 + j][n];
    unsigned short ah = f2bf_rne(a), bh = f2bf_rne(b);
    h0[j] = (short)ah; h1v[j] = (short)bh;
    l0[j] = (short)f2bf_rne(a - bf2f(ah));
    l1v[j] = (short)f2bf_rne(b - bf2f(bh));
  }
  size_t o = ((size_t)h * 64 + n) * NFEAT + k0 + kc;
  *(short8*)&wth[o]     = h0;
  *(short8*)&wth[o + 8] = h1v;
  *(short8*)&wtl[o]     = l0;
  *(short8*)&wtl[o + 8] = l1v;
}

// ---------------------------------------------------------------------------
// GEMM1 via split-bf16 MFMA: h[b,head,n,d] = x[row,:] @ W1[head]
// Block: 64 rows x 64 cols, 256 thr (4 waves; wave w owns rows 16w..16w+15).
// LDS rows padded to 72 ushort (144 B, 16B-aligned; frag reads <=2-way banks).
// Fragments (16x16x32, m89-verified): A lane: row=l&15, k=(l>>4)*8+j;
// B lane: col=l&15, k=(l>>4)*8+j  (wt[n][k] layout); D: col=l&15, row=(l>>4)*4+reg.
// ---------------------------------------------------------------------------
__global__ __launch_bounds__(256) void gemm1_mfma_kernel(
    const unsigned short* __restrict__ xhi, const unsigned short* __restrict__ xlo,
    const unsigned short* __restrict__ wth, const unsigned short* __restrict__ wtl,
    float* __restrict__ Y) {
  __shared__ unsigned short xsh[64][72], xsl[64][72], wsh[64][72], wsl[64][72];
  int tid = threadIdx.x;
  int w = tid >> 6, l = tid & 63;
  int row0 = blockIdx.x * 64;
  int head = blockIdx.y;
  const unsigned short* xh = xhi + (size_t)row0 * NFEAT;
  const unsigned short* xl = xlo + (size_t)row0 * NFEAT;
  const unsigned short* wh = wth + (size_t)head * 64 * NFEAT;
  const unsigned short* wl = wtl + (size_t)head * 64 * NFEAT;

  int sr = tid >> 2;            // staging row 0..63
  int sc = (tid & 3) * 16;      // staging col base {0,16,32,48}

  f32x4 acc[4];
#pragma unroll
  for (int nt = 0; nt < 4; ++nt) acc[nt] = (f32x4){0.f, 0.f, 0.f, 0.f};

  for (int k0 = 0; k0 < NFEAT; k0 += 64) {
    {
      const unsigned short* s0 = xh + (size_t)sr * NFEAT + k0 + sc;
      const unsigned short* s1 = xl + (size_t)sr * NFEAT + k0 + sc;
      const unsigned short* s2 = wh + (size_t)sr * NFEAT + k0 + sc;
      const unsigned short* s3 = wl + (size_t)sr * NFEAT + k0 + sc;
      *(short8*)&xsh[sr][sc]     = *(const short8*)s0;
      *(short8*)&xsh[sr][sc + 8] = *(const short8*)(s0 + 8);
      *(short8*)&xsl[sr][sc]     = *(const short8*)s1;
      *(short8*)&xsl[sr][sc + 8] = *(const short8*)(s1 + 8);
      *(short8*)&wsh[sr][sc]     = *(const short8*)s2;
      *(short8*)&wsh[sr][sc + 8] = *(const short8*)(s2 + 8);
      *(short8*)&wsl[sr][sc]     = *(const short8*)s3;
      *(short8*)&wsl[sr][sc + 8] = *(const short8*)(s3 + 8);
    }
    __syncthreads();
#pragma unroll
    for (int ks = 0; ks < 2; ++ks) {
      int ko = ks * 32 + (l >> 4) * 8;
      int ar = 16 * w + (l & 15);
      short8 ah = *(const short8*)&xsh[ar][ko];
      short8 al = *(const short8*)&xsl[ar][ko];
#pragma unroll
      for (int nt = 0; nt < 4; ++nt) {
        int br = 16 * nt + (l & 15);
        short8 bh = *(const short8*)&wsh[br][ko];
        short8 bl = *(const short8*)&wsl[br][ko];
        acc[nt] = __builtin_amdgcn_mfma_f32_16x16x32_bf16(ah, bh, acc[nt], 0, 0, 0);
        acc[nt] = __builtin_amdgcn_mfma_f32_16x16x32_bf16(ah, bl, acc[nt], 0, 0, 0);
        acc[nt] = __builtin_amdgcn_mfma_f32_16x16x32_bf16(al, bh, acc[nt], 0, 0, 0);
      }
    }
    __syncthreads();
  }

  int b = row0 >> 11;                  // 64-row tiles never straddle b (2048%64==0)
  int nbase = row0 & (N_ - 1);
#pragma unroll
  for (int nt = 0; nt < 4; ++nt) {
#pragma unroll
    for (int j = 0; j < 4; ++j) {
      int r = 16 * w + (l >> 4) * 4 + j;
      Y[(((size_t)(b * NHEADS + head)) * N_ + nbase + r) * 64 + 16 * nt + (l & 15)] =
          acc[nt][j];
    }
  }
}

// ---------------------------------------------------------------------------
// Register-tiled fp32 GEMM (kept for gemm2, K=256): Y = X @ W, 64x64 tile.
// ---------------------------------------------------------------------------
template <int K>
__global__ __launch_bounds__(256) void gemm_kernel(
    const float* __restrict__ X, const float* __restrict__ W, float* __restrict__ Y) {
  __shared__ float xs_t[64][68];   // [f][row]
  __shared__ float ws[64][68];     // [f][col]
  int tid = threadIdx.x;
  int tc4 = (tid & 15) * 4;        // col base
  int tr4 = (tid >> 4) * 4;        // row base
  int row0 = blockIdx.x * 64;
  const float* Xb = X + (size_t)row0 * K;
  const float* Wb = W;
  int sr = tid >> 2;
  int sc = (tid & 3) * 16;
  float4 acc[4];
#pragma unroll
  for (int i = 0; i < 4; ++i) acc[i] = make_float4(0.f, 0.f, 0.f, 0.f);

  for (int fc = 0; fc < K; fc += 64) {
    {
      const float* src = Xb + (size_t)sr * K + fc + sc;
      float v[16];
      *(float4*)&v[0]  = ((const float4*)src)[0];
      *(float4*)&v[4]  = ((const float4*)src)[1];
      *(float4*)&v[8]  = ((const float4*)src)[2];
      *(float4*)&v[12] = ((const float4*)src)[3];
#pragma unroll
      for (int j = 0; j < 16; ++j) xs_t[sc + j][sr] = v[j];
    }
    {
      const float* src = Wb + (size_t)(fc + sr) * 64 + sc;
      *(float4*)&ws[sr][sc]      = ((const float4*)src)[0];
      *(float4*)&ws[sr][sc + 4]  = ((const float4*)src)[1];
      *(float4*)&ws[sr][sc + 8]  = ((const float4*)src)[2];
      *(float4*)&ws[sr][sc + 12] = ((const float4*)src)[3];
    }
    __syncthreads();
#pragma unroll 8
    for (int f = 0; f < 64; ++f) {
      float4 xv = *(const float4*)&xs_t[f][tr4];
      float4 wv = *(const float4*)&ws[f][tc4];
      acc[0].x = fmaf(xv.x, wv.x, acc[0].x);
      acc[0].y = fmaf(xv.x, wv.y, acc[0].y);
      acc[0].z = fmaf(xv.x, wv.z, acc[0].z);
      acc[0].w = fmaf(xv.x, wv.w, acc[0].w);
      acc[1].x = fmaf(xv.y, wv.x, acc[1].x);
      acc[1].y = fmaf(xv.y, wv.y, acc[1].y);
      acc[1].z = fmaf(xv.y, wv.z, acc[1].z);
      acc[1].w = fmaf(xv.y, wv.w, acc[1].w);
      acc[2].x = fmaf(xv.z, wv.x, acc[2].x);
      acc[2].y = fmaf(xv.z, wv.y, acc[2].y);
      acc[2].z = fmaf(xv.z, wv.z, acc[2].z);
      acc[2].w = fmaf(xv.z, wv.w, acc[2].w);
      acc[3].x = fmaf(xv.w, wv.x, acc[3].x);
      acc[3].y = fmaf(xv.w, wv.y, acc[3].y);
      acc[3].z = fmaf(xv.w, wv.z, acc[3].z);
      acc[3].w = fmaf(xv.w, wv.w, acc[3].w);
    }
    __syncthreads();
  }
#pragma unroll
  for (int i = 0; i < 4; ++i) {
    int gr = row0 + tr4 + i;
    *(float4*)&Y[(size_t)gr * 64 + tc4] = acc[i];
  }
}

// ---------------------------------------------------------------------------
// Row dots: one wave per row, butterfly shuffle reduce.
// ---------------------------------------------------------------------------
template <int NH>
__global__ __launch_bounds__(256) void rowdot_kernel(
    const float* __restrict__ Hm, const float* __restrict__ a,
    float* __restrict__ ssrc, float* __restrict__ sdst) {
  int w = threadIdx.x >> 6, lane = threadIdx.x & 63;
  int gr = blockIdx.x * 4 + w;
  int hh = (NH > 1) ? ((gr >> 11) & (NH - 1)) : 0;
  float v = Hm[(size_t)gr * 64 + lane];
  float s1 = v * a[hh * 128 + lane];
  float s2 = v * a[hh * 128 + 64 + lane];
#pragma unroll
  for (int off = 32; off; off >>= 1) {
    s1 += __shfl_xor(s1, off);
    s2 += __shfl_xor(s2, off);
  }
  if (lane == 0) { ssrc[gr] = s1; sdst[gr] = s2; }
}

// ---------------------------------------------------------------------------
// Sparse attention aggregation, 8-wide software-pipelined neighbor loop.
// ---------------------------------------------------------------------------
__device__ __forceinline__ float sparse_agg(
    const float* __restrict__ plane, const float* __restrict__ sdb,
    const int* __restrict__ nb, int dg, float ss, int lane) {
  float acc0 = 0.f, acc1 = 0.f, den0 = 0.f, den1 = 0.f;
  int k = 0;
  for (; k + 8 <= dg; k += 8) {
    int m[8];
    float sv[8], hv[8];
#pragma unroll
    for (int j = 0; j < 8; ++j) m[j] = nb[k + j];
#pragma unroll
    for (int j = 0; j < 8; ++j) sv[j] = sdb[m[j]];
#pragma unroll
    for (int j = 0; j < 8; ++j) hv[j] = plane[(size_t)m[j] * 64 + lane];
#pragma unroll
    for (int j = 0; j < 8; ++j) {
      float s = ss + sv[j];
      float lr = s > 0.f ? s : LRELU_ALPHA * s;
      float ev = __expf(-lr);
      if (j & 1) { den1 += ev; acc1 = fmaf(ev, hv[j], acc1); }
      else       { den0 += ev; acc0 = fmaf(ev, hv[j], acc0); }
    }
  }
  for (; k < dg; ++k) {
    int m = nb[k];
    float s = ss + sdb[m];
    float lr = s > 0.f ? s : LRELU_ALPHA * s;
    float ev = __expf(-lr);
    den0 += ev;
    acc0 = fmaf(ev, plane[(size_t)m * 64 + lane], acc0);
  }
  return (acc0 + acc1) / (den0 + den1);
}

// ---------------------------------------------------------------------------
// Layer-1 sparse attention aggregation + ELU + head concat. One wave/(b,h,n).
// ---------------------------------------------------------------------------
__global__ __launch_bounds__(256) void attn1_kernel(
    const float* __restrict__ Hm, const float* __restrict__ ssrc,
    const float* __restrict__ sdst, const int* __restrict__ nbr,
    const int* __restrict__ deg, float* __restrict__ h1) {
  int w = threadIdx.x >> 6, lane = threadIdx.x & 63;
  int gr = blockIdx.x * 4 + w;        // 0..B*H*N
  int n = gr & (N_ - 1);
  int bh = gr >> 11;
  float o = sparse_agg(Hm + (size_t)bh * N_ * 64, sdst + (size_t)bh * N_,
                       nbr + n * MAXDEG, deg[n], ssrc[gr], lane);
  o = o > 0.f ? o : expm1f(o);
  int b = bh >> 2, hh = bh & 3;
  h1[((size_t)b * N_ + n) * (NHEADS * NHID) + hh * 64 + lane] = o;
}

// ---------------------------------------------------------------------------
// Layer-2 sparse attention aggregation + final ELU -> d_out. One wave/(b,n).
// ---------------------------------------------------------------------------
__global__ __launch_bounds__(256) void attn2_kernel(
    const float* __restrict__ G, const float* __restrict__ tsrc,
    const float* __restrict__ tdst, const int* __restrict__ nbr,
    const int* __restrict__ deg, float* __restrict__ out) {
  int w = threadIdx.x >> 6, lane = threadIdx.x & 63;
  int gr = blockIdx.x * 4 + w;        // 0..B*N
  int n = gr & (N_ - 1);
  int b = gr >> 11;
  float o = sparse_agg(G + (size_t)b * N_ * 64, tdst + (size_t)b * N_,
                       nbr + n * MAXDEG, deg[n], tsrc[gr], lane);
  out[(size_t)gr * 64 + lane] = o > 0.f ? o : expm1f(o);
}

// ---------------------------------------------------------------------------
extern "C" void kernel_launch(void* const* d_in, const int* in_sizes, int n_in,
                              void* d_out, int out_size, void* d_ws, size_t ws_size,
                              hipStream_t stream) {
  const float* x   = (const float*)d_in[0];   // [B,N,512]
  const float* adj = (const float*)d_in[1];   // [N,N]
  const float* W1  = (const float*)d_in[2];   // [H,512,64]
  const float* a1  = (const float*)d_in[3];   // [H,128]
  const float* W2  = (const float*)d_in[4];   // [256,64]
  const float* a2  = (const float*)d_in[5];   // [128]
  float* out = (float*)d_out;                 // [B,N,64] fp32

  char* ws = (char*)d_ws;
  float* h    = (float*)ws; ws += (size_t)B_ * NHEADS * N_ * 64 * 4;  // 8 MB  [B,H,N,64]
  float* h1   = (float*)ws; ws += (size_t)B_ * N_ * 256 * 4;          // 8 MB  [B,N,256]
  float* g    = (float*)ws; ws += (size_t)B_ * N_ * 64 * 4;           // 2 MB  [B,N,64]
  float* ssrc = (float*)ws; ws += (size_t)B_ * NHEADS * N_ * 4;
  float* sdst = (float*)ws; ws += (size_t)B_ * NHEADS * N_ * 4;
  float* tsrc = (float*)ws; ws += (size_t)B_ * N_ * 4;
  float* tdst = (float*)ws; ws += (size_t)B_ * N_ * 4;
  int*   nbr  = (int*)ws;   ws += (size_t)N_ * MAXDEG * 4;            // 1 MB
  int*   deg  = (int*)ws;   ws += (size_t)N_ * 4;
  ws = (char*)(((size_t)ws + 255) & ~(size_t)255);
  unsigned short* xhi = (unsigned short*)ws; ws += (size_t)B_ * N_ * NFEAT * 2;  // 8.4 MB
  unsigned short* xlo = (unsigned short*)ws; ws += (size_t)B_ * N_ * NFEAT * 2;  // 8.4 MB
  unsigned short* wth = (unsigned short*)ws; ws += (size_t)NHEADS * 64 * NFEAT * 2;
  unsigned short* wtl = (unsigned short*)ws; ws += (size_t)NHEADS * 64 * NFEAT * 2;

  build_adj_kernel<<<N_, 256, 0, stream>>>(adj, nbr, deg);
  prep_x_kernel<<<(B_ * N_ * NFEAT) / (256 * 8), 256, 0, stream>>>(x, xhi, xlo);
  prep_w_kernel<<<dim3(NFEAT / 64, NHEADS), 256, 0, stream>>>(W1, wth, wtl);
  gemm1_mfma_kernel<<<dim3(B_ * N_ / 64, NHEADS), 256, 0, stream>>>(xhi, xlo, wth, wtl, h);
  rowdot_kernel<NHEADS><<<B_ * NHEADS * N_ / 4, 256, 0, stream>>>(h, a1, ssrc, sdst);
  attn1_kernel<<<B_ * NHEADS * N_ / 4, 256, 0, stream>>>(h, ssrc, sdst, nbr, deg, h1);
  gemm_kernel<NHEADS * NHID><<<B_ * N_ / 64, 256, 0, stream>>>(h1, W2, g);
  rowdot_kernel<1><<<B_ * N_ / 4, 256, 0, stream>>>(g, a2, tsrc, tdst);
  attn2_kernel<<<B_ * N_ / 4, 256, 0, stream>>>(g, tsrc, tdst, nbr, deg, out);
}

// Round 9
// 149.216 us; speedup vs baseline: 1.8393x; 1.1194x over previous
//
#include <hip/hip_runtime.h>
#include <hip/hip_bf16.h>

constexpr int B_ = 4, N_ = 2048, NFEAT = 512, NHID = 64, NHEADS = 4, NCLASS = 64;
constexpr int MAXDEG = 128;
#define LRELU_ALPHA 0.2f

typedef __attribute__((ext_vector_type(8))) short short8;
typedef __attribute__((ext_vector_type(4))) float f32x4;

__device__ __forceinline__ unsigned short f2bf_rne(float f) {
  unsigned int u = __float_as_uint(f);
  unsigned int r = (u + 0x7FFFu + ((u >> 16) & 1u)) >> 16;
  return (unsigned short)r;
}
__device__ __forceinline__ float bf2f(unsigned short h) {
  return __uint_as_float(((unsigned int)h) << 16);
}

// ---------------------------------------------------------------------------
// build neighbor lists from dense binary adj. One block per row n.
// ---------------------------------------------------------------------------
__global__ __launch_bounds__(256) void build_adj_kernel(
    const float* __restrict__ adj, int* __restrict__ nbr, int* __restrict__ deg) {
  int n = blockIdx.x;
  int tid = threadIdx.x;
  __shared__ int cnt;
  if (tid == 0) cnt = 0;
  __syncthreads();
  for (int m = tid; m < N_; m += 256) {
    bool nz = adj[(size_t)n * N_ + m] != 0.0f;
    unsigned long long mask = __ballot(nz);
    int lane = tid & 63;
    int num = __popcll(mask);
    if (num) {               // wave-uniform
      int base = 0;
      if (lane == 0) base = atomicAdd(&cnt, num);
      base = __shfl(base, 0);
      if (nz) {
        int pos = base + __popcll(mask & ((1ull << lane) - 1ull));
        if (pos < MAXDEG) nbr[n * MAXDEG + pos] = m;
      }
    }
  }
  __syncthreads();
  if (tid == 0) deg[n] = cnt < MAXDEG ? cnt : MAXDEG;
}

// ---------------------------------------------------------------------------
// prep_x: split x (fp32) into hi/lo bf16 planes, 8 elements/thread.
// ---------------------------------------------------------------------------
__global__ __launch_bounds__(256) void prep_x_kernel(
    const float* __restrict__ x, unsigned short* __restrict__ xhi,
    unsigned short* __restrict__ xlo) {
  size_t idx = ((size_t)blockIdx.x * 256 + threadIdx.x) * 8;
  float4 v0 = *(const float4*)&x[idx];
  float4 v1 = *(const float4*)&x[idx + 4];
  float v[8] = {v0.x, v0.y, v0.z, v0.w, v1.x, v1.y, v1.z, v1.w};
  short8 sh, sl;
#pragma unroll
  for (int j = 0; j < 8; ++j) {
    unsigned short hi = f2bf_rne(v[j]);
    sh[j] = (short)hi;
    sl[j] = (short)f2bf_rne(v[j] - bf2f(hi));
  }
  *(short8*)&xhi[idx] = sh;
  *(short8*)&xlo[idx] = sl;
}

// ---------------------------------------------------------------------------
// prep_w<KK>: W[h][k][n] (KKx64 per h) -> transposed hi/lo bf16 wt*[h][n][k].
// ---------------------------------------------------------------------------
template <int KK>
__global__ __launch_bounds__(256) void prep_w_kernel(
    const float* __restrict__ W, unsigned short* __restrict__ wth,
    unsigned short* __restrict__ wtl) {
  __shared__ float ts[64][65];
  int h = blockIdx.y, k0 = blockIdx.x * 64;
  int tid = threadIdx.x;
  int kr = tid >> 2, nc = (tid & 3) * 16;
  const float* src = W + ((size_t)h * KK + k0 + kr) * 64 + nc;
#pragma unroll
  for (int j = 0; j < 4; ++j)
    *(float4*)&ts[kr][nc + 4 * j] = *(const float4*)(src + 4 * j);
  __syncthreads();
  int n = tid >> 2, kc = (tid & 3) * 16;
  short8 h0, h1v, l0, l1v;
#pragma unroll
  for (int j = 0; j < 8; ++j) {
    float a = ts[kc + j][n];
    float b = ts[kc + 8 + j][n];
    unsigned short ah = f2bf_rne(a), bh = f2bf_rne(b);
    h0[j] = (short)ah; h1v[j] = (short)bh;
    l0[j] = (short)f2bf_rne(a - bf2f(ah));
    l1v[j] = (short)f2bf_rne(b - bf2f(bh));
  }
  size_t o = ((size_t)h * 64 + n) * KK + k0 + kc;
  *(short8*)&wth[o]     = h0;
  *(short8*)&wth[o + 8] = h1v;
  *(short8*)&wtl[o]     = l0;
  *(short8*)&wtl[o + 8] = l1v;
}

// ---------------------------------------------------------------------------
// Split-bf16 MFMA GEMM + fused rowdot epilogue.
// MODE 0 (layer1): Y=h fp32 [b,n,head*64+d]; rowdot vs a1[head] (avec+head*128).
// MODE 1 (layer2): Y=g fp32 [row,64]; rowdot vs a2.
// ---------------------------------------------------------------------------
template <int K, int MODE>
__global__ __launch_bounds__(256) void gemm_mfma_kernel(
    const unsigned short* __restrict__ Xh, const unsigned short* __restrict__ Xl,
    const unsigned short* __restrict__ Wth, const unsigned short* __restrict__ Wtl,
    const float* __restrict__ avec, float* __restrict__ Y,
    float* __restrict__ so_src, float* __restrict__ so_dst) {
  __shared__ unsigned short xsh[64][72], xsl[64][72], wsh[64][72], wsl[64][72];
  int tid = threadIdx.x;
  int w = tid >> 6, l = tid & 63;
  int row0 = blockIdx.x * 64;
  int head = blockIdx.y;
  const unsigned short* xh = Xh + (size_t)row0 * K;
  const unsigned short* xl = Xl + (size_t)row0 * K;
  const unsigned short* wh = Wth + (size_t)head * 64 * K;
  const unsigned short* wl = Wtl + (size_t)head * 64 * K;
  const float* av = avec + head * 128;   // BUGFIX R6: per-head attention vector

  int sr = tid >> 2;            // staging row 0..63
  int sc = (tid & 3) * 16;      // staging col base {0,16,32,48}

  f32x4 acc[4];
#pragma unroll
  for (int nt = 0; nt < 4; ++nt) acc[nt] = (f32x4){0.f, 0.f, 0.f, 0.f};

  for (int k0 = 0; k0 < K; k0 += 64) {
    {
      const unsigned short* s0 = xh + (size_t)sr * K + k0 + sc;
      const unsigned short* s1 = xl + (size_t)sr * K + k0 + sc;
      const unsigned short* s2 = wh + (size_t)sr * K + k0 + sc;
      const unsigned short* s3 = wl + (size_t)sr * K + k0 + sc;
      *(short8*)&xsh[sr][sc]     = *(const short8*)s0;
      *(short8*)&xsh[sr][sc + 8] = *(const short8*)(s0 + 8);
      *(short8*)&xsl[sr][sc]     = *(const short8*)s1;
      *(short8*)&xsl[sr][sc + 8] = *(const short8*)(s1 + 8);
      *(short8*)&wsh[sr][sc]     = *(const short8*)s2;
      *(short8*)&wsh[sr][sc + 8] = *(const short8*)(s2 + 8);
      *(short8*)&wsl[sr][sc]     = *(const short8*)s3;
      *(short8*)&wsl[sr][sc + 8] = *(const short8*)(s3 + 8);
    }
    __syncthreads();
#pragma unroll
    for (int ks = 0; ks < 2; ++ks) {
      int ko = ks * 32 + (l >> 4) * 8;
      int ar = 16 * w + (l & 15);
      short8 ah = *(const short8*)&xsh[ar][ko];
      short8 al = *(const short8*)&xsl[ar][ko];
#pragma unroll
      for (int nt = 0; nt < 4; ++nt) {
        int br = 16 * nt + (l & 15);
        short8 bh = *(const short8*)&wsh[br][ko];
        short8 bl = *(const short8*)&wsl[br][ko];
        acc[nt] = __builtin_amdgcn_mfma_f32_16x16x32_bf16(ah, bh, acc[nt], 0, 0, 0);
        acc[nt] = __builtin_amdgcn_mfma_f32_16x16x32_bf16(ah, bl, acc[nt], 0, 0, 0);
        acc[nt] = __builtin_amdgcn_mfma_f32_16x16x32_bf16(al, bh, acc[nt], 0, 0, 0);
      }
    }
    __syncthreads();
  }

  int col = (l & 15);
  // ---- write Y ----
#pragma unroll
  for (int nt = 0; nt < 4; ++nt) {
#pragma unroll
    for (int j = 0; j < 4; ++j) {
      int r = 16 * w + (l >> 4) * 4 + j;
      size_t gr = row0 + r;
      if (MODE == 0)
        Y[gr * (NHEADS * 64) + head * 64 + 16 * nt + col] = acc[nt][j];
      else
        Y[gr * 64 + 16 * nt + col] = acc[nt][j];
    }
  }
  // ---- fused rowdot: s = <Yrow, a_src>, <Yrow, a_dst> ----
  float aS[4], aD[4];
#pragma unroll
  for (int nt = 0; nt < 4; ++nt) {
    aS[nt] = av[16 * nt + col];
    aD[nt] = av[64 + 16 * nt + col];
  }
  float s1[4] = {0.f, 0.f, 0.f, 0.f}, s2[4] = {0.f, 0.f, 0.f, 0.f};
#pragma unroll
  for (int nt = 0; nt < 4; ++nt)
#pragma unroll
    for (int j = 0; j < 4; ++j) {
      s1[j] = fmaf(acc[nt][j], aS[nt], s1[j]);
      s2[j] = fmaf(acc[nt][j], aD[nt], s2[j]);
    }
#pragma unroll
  for (int off = 1; off < 16; off <<= 1) {
#pragma unroll
    for (int j = 0; j < 4; ++j) {
      s1[j] += __shfl_xor(s1[j], off);
      s2[j] += __shfl_xor(s2[j], off);
    }
  }
  if (col == 0) {
#pragma unroll
    for (int j = 0; j < 4; ++j) {
      int r = 16 * w + (l >> 4) * 4 + j;
      int gr = row0 + r;
      size_t si;
      if (MODE == 0) {
        int b = gr >> 11, n = gr & (N_ - 1);
        si = (size_t)(b * NHEADS + head) * N_ + n;
      } else {
        si = gr;
      }
      so_src[si] = s1[j];
      so_dst[si] = s2[j];
    }
  }
}

// ---------------------------------------------------------------------------
// Sparse attention aggregation, 8-wide software-pipelined neighbor loop.
// RS = row stride of the feature plane.
// ---------------------------------------------------------------------------
template <int RS>
__device__ __forceinline__ float sparse_agg(
    const float* __restrict__ plane, const float* __restrict__ sdb,
    const int* __restrict__ nb, int dg, float ss, int lane) {
  float acc0 = 0.f, acc1 = 0.f, den0 = 0.f, den1 = 0.f;
  int k = 0;
  for (; k + 8 <= dg; k += 8) {
    int m[8];
    float sv[8], hv[8];
#pragma unroll
    for (int j = 0; j < 8; ++j) m[j] = nb[k + j];
#pragma unroll
    for (int j = 0; j < 8; ++j) sv[j] = sdb[m[j]];
#pragma unroll
    for (int j = 0; j < 8; ++j) hv[j] = plane[(size_t)m[j] * RS + lane];
#pragma unroll
    for (int j = 0; j < 8; ++j) {
      float s = ss + sv[j];
      float lr = s > 0.f ? s : LRELU_ALPHA * s;
      float ev = __expf(-lr);
      if (j & 1) { den1 += ev; acc1 = fmaf(ev, hv[j], acc1); }
      else       { den0 += ev; acc0 = fmaf(ev, hv[j], acc0); }
    }
  }
  for (; k < dg; ++k) {
    int m = nb[k];
    float s = ss + sdb[m];
    float lr = s > 0.f ? s : LRELU_ALPHA * s;
    float ev = __expf(-lr);
    den0 += ev;
    acc0 = fmaf(ev, plane[(size_t)m * RS + lane], acc0);
  }
  return (acc0 + acc1) / (den0 + den1);
}

// ---------------------------------------------------------------------------
// Layer-1 aggregation: one BLOCK per (b,n); 4 waves = 4 heads.
// nbr list staged in LDS once, shared. h layout [b,n,head*64+d].
// Output h1 written directly as split hi/lo bf16 [row][256].
// ---------------------------------------------------------------------------
__global__ __launch_bounds__(256) void attn1_kernel(
    const float* __restrict__ Hm, const float* __restrict__ ssrc,
    const float* __restrict__ sdst, const int* __restrict__ nbr,
    const int* __restrict__ deg, unsigned short* __restrict__ h1h,
    unsigned short* __restrict__ h1l) {
  int bn = blockIdx.x;               // 0..B*N-1
  int n = bn & (N_ - 1), b = bn >> 11;
  int w = threadIdx.x >> 6;          // head
  int lane = threadIdx.x & 63;
  __shared__ int lds_nbr[MAXDEG];
  int dg = deg[n];
  for (int k = threadIdx.x; k < dg; k += 256) lds_nbr[k] = nbr[n * MAXDEG + k];
  __syncthreads();
  int bh = b * NHEADS + w;
  float ss = ssrc[(size_t)bh * N_ + n];
  const float* sdb = sdst + (size_t)bh * N_;
  const float* plane = Hm + (size_t)b * N_ * (NHEADS * 64) + w * 64;
  float o = sparse_agg<NHEADS * 64>(plane, sdb, lds_nbr, dg, ss, lane);
  o = o > 0.f ? o : expm1f(o);
  unsigned short hi = f2bf_rne(o);
  size_t oi = (size_t)bn * (NHEADS * NHID) + w * 64 + lane;
  h1h[oi] = hi;
  h1l[oi] = f2bf_rne(o - bf2f(hi));
}

// ---------------------------------------------------------------------------
// Layer-2 aggregation + final ELU -> d_out. One wave per (b,n).
// ---------------------------------------------------------------------------
__global__ __launch_bounds__(256) void attn2_kernel(
    const float* __restrict__ G, const float* __restrict__ tsrc,
    const float* __restrict__ tdst, const int* __restrict__ nbr,
    const int* __restrict__ deg, float* __restrict__ out) {
  int w = threadIdx.x >> 6, lane = threadIdx.x & 63;
  int gr = blockIdx.x * 4 + w;        // 0..B*N
  int n = gr & (N_ - 1);
  int b = gr >> 11;
  float o = sparse_agg<64>(G + (size_t)b * N_ * 64, tdst + (size_t)b * N_,
                           nbr + n * MAXDEG, deg[n], tsrc[gr], lane);
  out[(size_t)gr * 64 + lane] = o > 0.f ? o : expm1f(o);
}

// ---------------------------------------------------------------------------
extern "C" void kernel_launch(void* const* d_in, const int* in_sizes, int n_in,
                              void* d_out, int out_size, void* d_ws, size_t ws_size,
                              hipStream_t stream) {
  const float* x   = (const float*)d_in[0];   // [B,N,512]
  const float* adj = (const float*)d_in[1];   // [N,N]
  const float* W1  = (const float*)d_in[2];   // [H,512,64]
  const float* a1  = (const float*)d_in[3];   // [H,128]
  const float* W2  = (const float*)d_in[4];   // [256,64]
  const float* a2  = (const float*)d_in[5];   // [128]
  float* out = (float*)d_out;                 // [B,N,64] fp32

  char* ws = (char*)d_ws;
  float* h    = (float*)ws; ws += (size_t)B_ * N_ * 256 * 4;          // 8 MB [b,n,h*64]
  float* g    = (float*)ws; ws += (size_t)B_ * N_ * 64 * 4;           // 2 MB
  float* ssrc = (float*)ws; ws += (size_t)B_ * NHEADS * N_ * 4;
  float* sdst = (float*)ws; ws += (size_t)B_ * NHEADS * N_ * 4;
  float* tsrc = (float*)ws; ws += (size_t)B_ * N_ * 4;
  float* tdst = (float*)ws; ws += (size_t)B_ * N_ * 4;
  int*   nbr  = (int*)ws;   ws += (size_t)N_ * MAXDEG * 4;            // 1 MB
  int*   deg  = (int*)ws;   ws += (size_t)N_ * 4;
  ws = (char*)(((size_t)ws + 255) & ~(size_t)255);
  unsigned short* xhi  = (unsigned short*)ws; ws += (size_t)B_ * N_ * NFEAT * 2; // 8.4 MB
  unsigned short* xlo  = (unsigned short*)ws; ws += (size_t)B_ * N_ * NFEAT * 2; // 8.4 MB
  unsigned short* wt1h = (unsigned short*)ws; ws += (size_t)NHEADS * 64 * NFEAT * 2;
  unsigned short* wt1l = (unsigned short*)ws; ws += (size_t)NHEADS * 64 * NFEAT * 2;
  unsigned short* wt2h = (unsigned short*)ws; ws += (size_t)64 * 256 * 2;
  unsigned short* wt2l = (unsigned short*)ws; ws += (size_t)64 * 256 * 2;
  unsigned short* h1h  = (unsigned short*)ws; ws += (size_t)B_ * N_ * 256 * 2;   // 4.2 MB
  unsigned short* h1l  = (unsigned short*)ws; ws += (size_t)B_ * N_ * 256 * 2;   // 4.2 MB

  build_adj_kernel<<<N_, 256, 0, stream>>>(adj, nbr, deg);
  prep_x_kernel<<<(B_ * N_ * NFEAT) / (256 * 8), 256, 0, stream>>>(x, xhi, xlo);
  prep_w_kernel<NFEAT><<<dim3(NFEAT / 64, NHEADS), 256, 0, stream>>>(W1, wt1h, wt1l);
  prep_w_kernel<256><<<dim3(256 / 64, 1), 256, 0, stream>>>(W2, wt2h, wt2l);
  gemm_mfma_kernel<NFEAT, 0><<<dim3(B_ * N_ / 64, NHEADS), 256, 0, stream>>>(
      xhi, xlo, wt1h, wt1l, a1, h, ssrc, sdst);
  attn1_kernel<<<B_ * N_, 256, 0, stream>>>(h, ssrc, sdst, nbr, deg, h1h, h1l);
  gemm_mfma_kernel<256, 1><<<dim3(B_ * N_ / 64, 1), 256, 0, stream>>>(
      h1h, h1l, wt2h, wt2l, a2, g, tsrc, tdst);
  attn2_kernel<<<B_ * N_ / 4, 256, 0, stream>>>(g, tsrc, tdst, nbr, deg, out);
}

// Round 10
// 144.861 us; speedup vs baseline: 1.8946x; 1.0301x over previous
//
#include <hip/hip_runtime.h>
#include <hip/hip_bf16.h>

constexpr int B_ = 4, N_ = 2048, NFEAT = 512, NHID = 64, NHEADS = 4, NCLASS = 64;
constexpr int MAXDEG = 128;
#define LRELU_ALPHA 0.2f

typedef __attribute__((ext_vector_type(8))) short short8;
typedef __attribute__((ext_vector_type(4))) float f32x4;

__device__ __forceinline__ unsigned short f2bf_rne(float f) {
  unsigned int u = __float_as_uint(f);
  unsigned int r = (u + 0x7FFFu + ((u >> 16) & 1u)) >> 16;
  return (unsigned short)r;
}
__device__ __forceinline__ float bf2f(unsigned short h) {
  return __uint_as_float(((unsigned int)h) << 16);
}

// ---------------------------------------------------------------------------
// prep_kernel: fused [adjacency-list build | W1 transpose-split | W2 t-split].
// Block ranges: [0,2048) adj rows; [2048,2080) W1 tiles; [2080,2084) W2 tiles.
// Whole blocks take one branch -> no divergence. LDS = max of both paths.
// ---------------------------------------------------------------------------
__global__ __launch_bounds__(256) void prep_kernel(
    const float* __restrict__ adj, int* __restrict__ nbr, int* __restrict__ deg,
    const float* __restrict__ W1, unsigned short* __restrict__ wt1h,
    unsigned short* __restrict__ wt1l, const float* __restrict__ W2,
    unsigned short* __restrict__ wt2h, unsigned short* __restrict__ wt2l) {
  __shared__ float ts[64][65];
  __shared__ int cnt;
  int bid = blockIdx.x;
  int tid = threadIdx.x;
  if (bid < N_) {
    // ---- adjacency build: one block per row n ----
    int n = bid;
    if (tid == 0) cnt = 0;
    __syncthreads();
    for (int m = tid; m < N_; m += 256) {
      bool nz = adj[(size_t)n * N_ + m] != 0.0f;
      unsigned long long mask = __ballot(nz);
      int lane = tid & 63;
      int num = __popcll(mask);
      if (num) {               // wave-uniform
        int base = 0;
        if (lane == 0) base = atomicAdd(&cnt, num);
        base = __shfl(base, 0);
        if (nz) {
          int pos = base + __popcll(mask & ((1ull << lane) - 1ull));
          if (pos < MAXDEG) nbr[n * MAXDEG + pos] = m;
        }
      }
    }
    __syncthreads();
    if (tid == 0) deg[n] = cnt < MAXDEG ? cnt : MAXDEG;
  } else {
    // ---- weight transpose-split: W[h][k][n] -> wt[h][n][k] hi/lo bf16 ----
    int wk = bid - N_;
    const float* W;
    unsigned short *wth, *wtl;
    int KK, h, k0;
    if (wk < 32) { W = W1; wth = wt1h; wtl = wt1l; KK = 512; h = wk >> 3; k0 = (wk & 7) * 64; }
    else { wk -= 32; W = W2; wth = wt2h; wtl = wt2l; KK = 256; h = 0; k0 = wk * 64; }
    int kr = tid >> 2, nc = (tid & 3) * 16;
    const float* src = W + ((size_t)h * KK + k0 + kr) * 64 + nc;
#pragma unroll
    for (int j = 0; j < 4; ++j)
      *(float4*)&ts[kr][nc + 4 * j] = *(const float4*)(src + 4 * j);
    __syncthreads();
    int n = tid >> 2, kc = (tid & 3) * 16;
    short8 h0, h1v, l0, l1v;
#pragma unroll
    for (int j = 0; j < 8; ++j) {
      float a = ts[kc + j][n];
      float b = ts[kc + 8 + j][n];
      unsigned short ah = f2bf_rne(a), bh = f2bf_rne(b);
      h0[j] = (short)ah; h1v[j] = (short)bh;
      l0[j] = (short)f2bf_rne(a - bf2f(ah));
      l1v[j] = (short)f2bf_rne(b - bf2f(bh));
    }
    size_t o = ((size_t)h * 64 + n) * KK + k0 + kc;
    *(short8*)&wth[o]     = h0;
    *(short8*)&wth[o + 8] = h1v;
    *(short8*)&wtl[o]     = l0;
    *(short8*)&wtl[o + 8] = l1v;
  }
}

// ---------------------------------------------------------------------------
// Split-bf16 MFMA GEMM + fused rowdot epilogue.
// MODE 0 (layer1): X = fp32 (split to hi/lo bf16 IN-KERNEL during staging);
//   Y=h fp32 [b,n,head*64+d]; rowdot vs a1[head] (avec+head*128).
// MODE 1 (layer2): X = pre-split ushort hi/lo (h1 from attn1);
//   Y=g fp32 [row,64]; rowdot vs a2.
// Block 64x64, 4 waves, 16x16x32 MFMA, 3-term split (xh*wh + xh*wl + xl*wh).
// ---------------------------------------------------------------------------
template <int K, int MODE>
__global__ __launch_bounds__(256) void gemm_mfma_kernel(
    const float* __restrict__ Xf, const unsigned short* __restrict__ Xh,
    const unsigned short* __restrict__ Xl, const unsigned short* __restrict__ Wth,
    const unsigned short* __restrict__ Wtl, const float* __restrict__ avec,
    float* __restrict__ Y, float* __restrict__ so_src, float* __restrict__ so_dst) {
  __shared__ unsigned short xsh[64][72], xsl[64][72], wsh[64][72], wsl[64][72];
  int tid = threadIdx.x;
  int w = tid >> 6, l = tid & 63;
  int row0 = blockIdx.x * 64;
  int head = blockIdx.y;
  const unsigned short* wh = Wth + (size_t)head * 64 * K;
  const unsigned short* wl = Wtl + (size_t)head * 64 * K;
  const float* av = avec + head * 128;   // per-head attention vector

  int sr = tid >> 2;            // staging row 0..63
  int sc = (tid & 3) * 16;      // staging col base {0,16,32,48}

  f32x4 acc[4];
#pragma unroll
  for (int nt = 0; nt < 4; ++nt) acc[nt] = (f32x4){0.f, 0.f, 0.f, 0.f};

  for (int k0 = 0; k0 < K; k0 += 64) {
    if (MODE == 0) {
      // stage X from fp32, splitting hi/lo in-kernel (same math as prep_x did)
      const float* s0 = Xf + (size_t)(row0 + sr) * K + k0 + sc;
      float4 f0 = ((const float4*)s0)[0];
      float4 f1 = ((const float4*)s0)[1];
      float4 f2 = ((const float4*)s0)[2];
      float4 f3 = ((const float4*)s0)[3];
      float v[16] = {f0.x, f0.y, f0.z, f0.w, f1.x, f1.y, f1.z, f1.w,
                     f2.x, f2.y, f2.z, f2.w, f3.x, f3.y, f3.z, f3.w};
      short8 hi0, hi1, lo0, lo1;
#pragma unroll
      for (int j = 0; j < 8; ++j) {
        unsigned short hh = f2bf_rne(v[j]);
        hi0[j] = (short)hh;
        lo0[j] = (short)f2bf_rne(v[j] - bf2f(hh));
        unsigned short hh1 = f2bf_rne(v[8 + j]);
        hi1[j] = (short)hh1;
        lo1[j] = (short)f2bf_rne(v[8 + j] - bf2f(hh1));
      }
      *(short8*)&xsh[sr][sc]     = hi0;
      *(short8*)&xsh[sr][sc + 8] = hi1;
      *(short8*)&xsl[sr][sc]     = lo0;
      *(short8*)&xsl[sr][sc + 8] = lo1;
    } else {
      const unsigned short* s0 = Xh + (size_t)(row0 + sr) * K + k0 + sc;
      const unsigned short* s1 = Xl + (size_t)(row0 + sr) * K + k0 + sc;
      *(short8*)&xsh[sr][sc]     = *(const short8*)s0;
      *(short8*)&xsh[sr][sc + 8] = *(const short8*)(s0 + 8);
      *(short8*)&xsl[sr][sc]     = *(const short8*)s1;
      *(short8*)&xsl[sr][sc + 8] = *(const short8*)(s1 + 8);
    }
    {
      const unsigned short* s2 = wh + (size_t)sr * K + k0 + sc;
      const unsigned short* s3 = wl + (size_t)sr * K + k0 + sc;
      *(short8*)&wsh[sr][sc]     = *(const short8*)s2;
      *(short8*)&wsh[sr][sc + 8] = *(const short8*)(s2 + 8);
      *(short8*)&wsl[sr][sc]     = *(const short8*)s3;
      *(short8*)&wsl[sr][sc + 8] = *(const short8*)(s3 + 8);
    }
    __syncthreads();
#pragma unroll
    for (int ks = 0; ks < 2; ++ks) {
      int ko = ks * 32 + (l >> 4) * 8;
      int ar = 16 * w + (l & 15);
      short8 ah = *(const short8*)&xsh[ar][ko];
      short8 al = *(const short8*)&xsl[ar][ko];
#pragma unroll
      for (int nt = 0; nt < 4; ++nt) {
        int br = 16 * nt + (l & 15);
        short8 bh = *(const short8*)&wsh[br][ko];
        short8 bl = *(const short8*)&wsl[br][ko];
        acc[nt] = __builtin_amdgcn_mfma_f32_16x16x32_bf16(ah, bh, acc[nt], 0, 0, 0);
        acc[nt] = __builtin_amdgcn_mfma_f32_16x16x32_bf16(ah, bl, acc[nt], 0, 0, 0);
        acc[nt] = __builtin_amdgcn_mfma_f32_16x16x32_bf16(al, bh, acc[nt], 0, 0, 0);
      }
    }
    __syncthreads();
  }

  int col = (l & 15);
  // ---- write Y ----
#pragma unroll
  for (int nt = 0; nt < 4; ++nt) {
#pragma unroll
    for (int j = 0; j < 4; ++j) {
      int r = 16 * w + (l >> 4) * 4 + j;
      size_t gr = row0 + r;
      if (MODE == 0)
        Y[gr * (NHEADS * 64) + head * 64 + 16 * nt + col] = acc[nt][j];
      else
        Y[gr * 64 + 16 * nt + col] = acc[nt][j];
    }
  }
  // ---- fused rowdot: s = <Yrow, a_src>, <Yrow, a_dst> ----
  float aS[4], aD[4];
#pragma unroll
  for (int nt = 0; nt < 4; ++nt) {
    aS[nt] = av[16 * nt + col];
    aD[nt] = av[64 + 16 * nt + col];
  }
  float s1[4] = {0.f, 0.f, 0.f, 0.f}, s2[4] = {0.f, 0.f, 0.f, 0.f};
#pragma unroll
  for (int nt = 0; nt < 4; ++nt)
#pragma unroll
    for (int j = 0; j < 4; ++j) {
      s1[j] = fmaf(acc[nt][j], aS[nt], s1[j]);
      s2[j] = fmaf(acc[nt][j], aD[nt], s2[j]);
    }
#pragma unroll
  for (int off = 1; off < 16; off <<= 1) {
#pragma unroll
    for (int j = 0; j < 4; ++j) {
      s1[j] += __shfl_xor(s1[j], off);
      s2[j] += __shfl_xor(s2[j], off);
    }
  }
  if (col == 0) {
#pragma unroll
    for (int j = 0; j < 4; ++j) {
      int r = 16 * w + (l >> 4) * 4 + j;
      int gr = row0 + r;
      size_t si;
      if (MODE == 0) {
        int b = gr >> 11, n = gr & (N_ - 1);
        si = (size_t)(b * NHEADS + head) * N_ + n;
      } else {
        si = gr;
      }
      so_src[si] = s1[j];
      so_dst[si] = s2[j];
    }
  }
}

// ---------------------------------------------------------------------------
// Sparse attention aggregation, 8-wide software-pipelined neighbor loop.
// RS = row stride of the feature plane.
// ---------------------------------------------------------------------------
template <int RS>
__device__ __forceinline__ float sparse_agg(
    const float* __restrict__ plane, const float* __restrict__ sdb,
    const int* __restrict__ nb, int dg, float ss, int lane) {
  float acc0 = 0.f, acc1 = 0.f, den0 = 0.f, den1 = 0.f;
  int k = 0;
  for (; k + 8 <= dg; k += 8) {
    int m[8];
    float sv[8], hv[8];
#pragma unroll
    for (int j = 0; j < 8; ++j) m[j] = nb[k + j];
#pragma unroll
    for (int j = 0; j < 8; ++j) sv[j] = sdb[m[j]];
#pragma unroll
    for (int j = 0; j < 8; ++j) hv[j] = plane[(size_t)m[j] * RS + lane];
#pragma unroll
    for (int j = 0; j < 8; ++j) {
      float s = ss + sv[j];
      float lr = s > 0.f ? s : LRELU_ALPHA * s;
      float ev = __expf(-lr);
      if (j & 1) { den1 += ev; acc1 = fmaf(ev, hv[j], acc1); }
      else       { den0 += ev; acc0 = fmaf(ev, hv[j], acc0); }
    }
  }
  for (; k < dg; ++k) {
    int m = nb[k];
    float s = ss + sdb[m];
    float lr = s > 0.f ? s : LRELU_ALPHA * s;
    float ev = __expf(-lr);
    den0 += ev;
    acc0 = fmaf(ev, plane[(size_t)m * RS + lane], acc0);
  }
  return (acc0 + acc1) / (den0 + den1);
}

// ---------------------------------------------------------------------------
// Layer-1 aggregation: one BLOCK per (b,n); 4 waves = 4 heads.
// nbr list staged in LDS once, shared. h layout [b,n,head*64+d].
// Output h1 written directly as split hi/lo bf16 [row][256].
// ---------------------------------------------------------------------------
__global__ __launch_bounds__(256) void attn1_kernel(
    const float* __restrict__ Hm, const float* __restrict__ ssrc,
    const float* __restrict__ sdst, const int* __restrict__ nbr,
    const int* __restrict__ deg, unsigned short* __restrict__ h1h,
    unsigned short* __restrict__ h1l) {
  int bn = blockIdx.x;               // 0..B*N-1
  int n = bn & (N_ - 1), b = bn >> 11;
  int w = threadIdx.x >> 6;          // head
  int lane = threadIdx.x & 63;
  __shared__ int lds_nbr[MAXDEG];
  int dg = deg[n];
  for (int k = threadIdx.x; k < dg; k += 256) lds_nbr[k] = nbr[n * MAXDEG + k];
  __syncthreads();
  int bh = b * NHEADS + w;
  float ss = ssrc[(size_t)bh * N_ + n];
  const float* sdb = sdst + (size_t)bh * N_;
  const float* plane = Hm + (size_t)b * N_ * (NHEADS * 64) + w * 64;
  float o = sparse_agg<NHEADS * 64>(plane, sdb, lds_nbr, dg, ss, lane);
  o = o > 0.f ? o : expm1f(o);
  unsigned short hi = f2bf_rne(o);
  size_t oi = (size_t)bn * (NHEADS * NHID) + w * 64 + lane;
  h1h[oi] = hi;
  h1l[oi] = f2bf_rne(o - bf2f(hi));
}

// ---------------------------------------------------------------------------
// Layer-2 aggregation + final ELU -> d_out. One wave per (b,n).
// ---------------------------------------------------------------------------
__global__ __launch_bounds__(256) void attn2_kernel(
    const float* __restrict__ G, const float* __restrict__ tsrc,
    const float* __restrict__ tdst, const int* __restrict__ nbr,
    const int* __restrict__ deg, float* __restrict__ out) {
  int w = threadIdx.x >> 6, lane = threadIdx.x & 63;
  int gr = blockIdx.x * 4 + w;        // 0..B*N
  int n = gr & (N_ - 1);
  int b = gr >> 11;
  float o = sparse_agg<64>(G + (size_t)b * N_ * 64, tdst + (size_t)b * N_,
                           nbr + n * MAXDEG, deg[n], tsrc[gr], lane);
  out[(size_t)gr * 64 + lane] = o > 0.f ? o : expm1f(o);
}

// ---------------------------------------------------------------------------
extern "C" void kernel_launch(void* const* d_in, const int* in_sizes, int n_in,
                              void* d_out, int out_size, void* d_ws, size_t ws_size,
                              hipStream_t stream) {
  const float* x   = (const float*)d_in[0];   // [B,N,512]
  const float* adj = (const float*)d_in[1];   // [N,N]
  const float* W1  = (const float*)d_in[2];   // [H,512,64]
  const float* a1  = (const float*)d_in[3];   // [H,128]
  const float* W2  = (const float*)d_in[4];   // [256,64]
  const float* a2  = (const float*)d_in[5];   // [128]
  float* out = (float*)d_out;                 // [B,N,64] fp32

  char* ws = (char*)d_ws;
  float* h    = (float*)ws; ws += (size_t)B_ * N_ * 256 * 4;          // 8 MB [b,n,h*64]
  float* g    = (float*)ws; ws += (size_t)B_ * N_ * 64 * 4;           // 2 MB
  float* ssrc = (float*)ws; ws += (size_t)B_ * NHEADS * N_ * 4;
  float* sdst = (float*)ws; ws += (size_t)B_ * NHEADS * N_ * 4;
  float* tsrc = (float*)ws; ws += (size_t)B_ * N_ * 4;
  float* tdst = (float*)ws; ws += (size_t)B_ * N_ * 4;
  int*   nbr  = (int*)ws;   ws += (size_t)N_ * MAXDEG * 4;            // 1 MB
  int*   deg  = (int*)ws;   ws += (size_t)N_ * 4;
  ws = (char*)(((size_t)ws + 255) & ~(size_t)255);
  unsigned short* wt1h = (unsigned short*)ws; ws += (size_t)NHEADS * 64 * NFEAT * 2;
  unsigned short* wt1l = (unsigned short*)ws; ws += (size_t)NHEADS * 64 * NFEAT * 2;
  unsigned short* wt2h = (unsigned short*)ws; ws += (size_t)64 * 256 * 2;
  unsigned short* wt2l = (unsigned short*)ws; ws += (size_t)64 * 256 * 2;
  unsigned short* h1h  = (unsigned short*)ws; ws += (size_t)B_ * N_ * 256 * 2;   // 4.2 MB
  unsigned short* h1l  = (unsigned short*)ws; ws += (size_t)B_ * N_ * 256 * 2;   // 4.2 MB

  // prep: blocks [0,2048) adj | [2048,2080) W1 | [2080,2084) W2
  prep_kernel<<<N_ + 32 + 4, 256, 0, stream>>>(adj, nbr, deg, W1, wt1h, wt1l,
                                               W2, wt2h, wt2l);
  gemm_mfma_kernel<NFEAT, 0><<<dim3(B_ * N_ / 64, NHEADS), 256, 0, stream>>>(
      x, nullptr, nullptr, wt1h, wt1l, a1, h, ssrc, sdst);
  attn1_kernel<<<B_ * N_, 256, 0, stream>>>(h, ssrc, sdst, nbr, deg, h1h, h1l);
  gemm_mfma_kernel<256, 1><<<dim3(B_ * N_ / 64, 1), 256, 0, stream>>>(
      nullptr, h1h, h1l, wt2h, wt2l, a2, g, tsrc, tdst);
  attn2_kernel<<<B_ * N_ / 4, 256, 0, stream>>>(g, tsrc, tdst, nbr, deg, out);
}

// Round 11
// 144.647 us; speedup vs baseline: 1.8974x; 1.0015x over previous
//
#include <hip/hip_runtime.h>
#include <hip/hip_bf16.h>

constexpr int B_ = 4, N_ = 2048, NFEAT = 512, NHID = 64, NHEADS = 4, NCLASS = 64;
constexpr int MAXDEG = 128;
#define LRELU_ALPHA 0.2f

typedef __attribute__((ext_vector_type(8))) short short8;
typedef __attribute__((ext_vector_type(4))) float f32x4;

__device__ __forceinline__ unsigned short f2bf_rne(float f) {
  unsigned int u = __float_as_uint(f);
  unsigned int r = (u + 0x7FFFu + ((u >> 16) & 1u)) >> 16;
  return (unsigned short)r;
}
__device__ __forceinline__ float bf2f(unsigned short h) {
  return __uint_as_float(((unsigned int)h) << 16);
}

// ---------------------------------------------------------------------------
// prep_kernel: fused [adjacency-list build | W1 transpose-split | W2 t-split].
// Block ranges: [0,2048) adj rows; [2048,2080) W1 tiles; [2080,2084) W2 tiles.
// ---------------------------------------------------------------------------
__global__ __launch_bounds__(256) void prep_kernel(
    const float* __restrict__ adj, int* __restrict__ nbr, int* __restrict__ deg,
    const float* __restrict__ W1, unsigned short* __restrict__ wt1h,
    unsigned short* __restrict__ wt1l, const float* __restrict__ W2,
    unsigned short* __restrict__ wt2h, unsigned short* __restrict__ wt2l) {
  __shared__ float ts[64][65];
  __shared__ int cnt;
  int bid = blockIdx.x;
  int tid = threadIdx.x;
  if (bid < N_) {
    int n = bid;
    if (tid == 0) cnt = 0;
    __syncthreads();
    for (int m = tid; m < N_; m += 256) {
      bool nz = adj[(size_t)n * N_ + m] != 0.0f;
      unsigned long long mask = __ballot(nz);
      int lane = tid & 63;
      int num = __popcll(mask);
      if (num) {               // wave-uniform
        int base = 0;
        if (lane == 0) base = atomicAdd(&cnt, num);
        base = __shfl(base, 0);
        if (nz) {
          int pos = base + __popcll(mask & ((1ull << lane) - 1ull));
          if (pos < MAXDEG) nbr[n * MAXDEG + pos] = m;
        }
      }
    }
    __syncthreads();
    if (tid == 0) deg[n] = cnt < MAXDEG ? cnt : MAXDEG;
  } else {
    int wk = bid - N_;
    const float* W;
    unsigned short *wth, *wtl;
    int KK, h, k0;
    if (wk < 32) { W = W1; wth = wt1h; wtl = wt1l; KK = 512; h = wk >> 3; k0 = (wk & 7) * 64; }
    else { wk -= 32; W = W2; wth = wt2h; wtl = wt2l; KK = 256; h = 0; k0 = wk * 64; }
    int kr = tid >> 2, nc = (tid & 3) * 16;
    const float* src = W + ((size_t)h * KK + k0 + kr) * 64 + nc;
#pragma unroll
    for (int j = 0; j < 4; ++j)
      *(float4*)&ts[kr][nc + 4 * j] = *(const float4*)(src + 4 * j);
    __syncthreads();
    int n = tid >> 2, kc = (tid & 3) * 16;
    short8 h0, h1v, l0, l1v;
#pragma unroll
    for (int j = 0; j < 8; ++j) {
      float a = ts[kc + j][n];
      float b = ts[kc + 8 + j][n];
      unsigned short ah = f2bf_rne(a), bh = f2bf_rne(b);
      h0[j] = (short)ah; h1v[j] = (short)bh;
      l0[j] = (short)f2bf_rne(a - bf2f(ah));
      l1v[j] = (short)f2bf_rne(b - bf2f(bh));
    }
    size_t o = ((size_t)h * 64 + n) * KK + k0 + kc;
    *(short8*)&wth[o]     = h0;
    *(short8*)&wth[o + 8] = h1v;
    *(short8*)&wtl[o]     = l0;
    *(short8*)&wtl[o + 8] = l1v;
  }
}

// ---------------------------------------------------------------------------
// Split-bf16 MFMA GEMM + fused rowdot epilogue.
// MODE 0 (layer1): X = fp32 (split in-kernel during staging); 1-D grid of 512,
//   XCD-grouped mapping: blocks {bid,bid+8,bid+16,bid+24} (same XCD under
//   bid%8 round-robin) share one row-tile -> x tile L2-resident across heads.
// MODE 1 (layer2): X = pre-split ushort hi/lo; grid (128,1).
// ---------------------------------------------------------------------------
template <int K, int MODE>
__global__ __launch_bounds__(256) void gemm_mfma_kernel(
    const float* __restrict__ Xf, const unsigned short* __restrict__ Xh,
    const unsigned short* __restrict__ Xl, const unsigned short* __restrict__ Wth,
    const unsigned short* __restrict__ Wtl, const float* __restrict__ avec,
    float* __restrict__ Y, float* __restrict__ so_src, float* __restrict__ so_dst) {
  __shared__ unsigned short xsh[64][72], xsl[64][72], wsh[64][72], wsl[64][72];
  int tid = threadIdx.x;
  int w = tid >> 6, l = tid & 63;
  int row0, head;
  if (MODE == 0) {
    // bid = q*32 + h*8 + x  ->  rowtile = q*8 + x, head = h
    int bid = blockIdx.x;
    int xcd = bid & 7, hh = (bid >> 3) & 3, q = bid >> 5;
    row0 = (q * 8 + xcd) * 64;
    head = hh;
  } else {
    row0 = blockIdx.x * 64;
    head = 0;
  }
  const unsigned short* wh = Wth + (size_t)head * 64 * K;
  const unsigned short* wl = Wtl + (size_t)head * 64 * K;
  const float* av = avec + head * 128;   // per-head attention vector

  int sr = tid >> 2;            // staging row 0..63
  int sc = (tid & 3) * 16;      // staging col base {0,16,32,48}

  f32x4 acc[4];
#pragma unroll
  for (int nt = 0; nt < 4; ++nt) acc[nt] = (f32x4){0.f, 0.f, 0.f, 0.f};

  for (int k0 = 0; k0 < K; k0 += 64) {
    if (MODE == 0) {
      const float* s0 = Xf + (size_t)(row0 + sr) * K + k0 + sc;
      float4 f0 = ((const float4*)s0)[0];
      float4 f1 = ((const float4*)s0)[1];
      float4 f2 = ((const float4*)s0)[2];
      float4 f3 = ((const float4*)s0)[3];
      float v[16] = {f0.x, f0.y, f0.z, f0.w, f1.x, f1.y, f1.z, f1.w,
                     f2.x, f2.y, f2.z, f2.w, f3.x, f3.y, f3.z, f3.w};
      short8 hi0, hi1, lo0, lo1;
#pragma unroll
      for (int j = 0; j < 8; ++j) {
        unsigned short hh = f2bf_rne(v[j]);
        hi0[j] = (short)hh;
        lo0[j] = (short)f2bf_rne(v[j] - bf2f(hh));
        unsigned short hh1 = f2bf_rne(v[8 + j]);
        hi1[j] = (short)hh1;
        lo1[j] = (short)f2bf_rne(v[8 + j] - bf2f(hh1));
      }
      *(short8*)&xsh[sr][sc]     = hi0;
      *(short8*)&xsh[sr][sc + 8] = hi1;
      *(short8*)&xsl[sr][sc]     = lo0;
      *(short8*)&xsl[sr][sc + 8] = lo1;
    } else {
      const unsigned short* s0 = Xh + (size_t)(row0 + sr) * K + k0 + sc;
      const unsigned short* s1 = Xl + (size_t)(row0 + sr) * K + k0 + sc;
      *(short8*)&xsh[sr][sc]     = *(const short8*)s0;
      *(short8*)&xsh[sr][sc + 8] = *(const short8*)(s0 + 8);
      *(short8*)&xsl[sr][sc]     = *(const short8*)s1;
      *(short8*)&xsl[sr][sc + 8] = *(const short8*)(s1 + 8);
    }
    {
      const unsigned short* s2 = wh + (size_t)sr * K + k0 + sc;
      const unsigned short* s3 = wl + (size_t)sr * K + k0 + sc;
      *(short8*)&wsh[sr][sc]     = *(const short8*)s2;
      *(short8*)&wsh[sr][sc + 8] = *(const short8*)(s2 + 8);
      *(short8*)&wsl[sr][sc]     = *(const short8*)s3;
      *(short8*)&wsl[sr][sc + 8] = *(const short8*)(s3 + 8);
    }
    __syncthreads();
#pragma unroll
    for (int ks = 0; ks < 2; ++ks) {
      int ko = ks * 32 + (l >> 4) * 8;
      int ar = 16 * w + (l & 15);
      short8 ah = *(const short8*)&xsh[ar][ko];
      short8 al = *(const short8*)&xsl[ar][ko];
#pragma unroll
      for (int nt = 0; nt < 4; ++nt) {
        int br = 16 * nt + (l & 15);
        short8 bh = *(const short8*)&wsh[br][ko];
        short8 bl = *(const short8*)&wsl[br][ko];
        acc[nt] = __builtin_amdgcn_mfma_f32_16x16x32_bf16(ah, bh, acc[nt], 0, 0, 0);
        acc[nt] = __builtin_amdgcn_mfma_f32_16x16x32_bf16(ah, bl, acc[nt], 0, 0, 0);
        acc[nt] = __builtin_amdgcn_mfma_f32_16x16x32_bf16(al, bh, acc[nt], 0, 0, 0);
      }
    }
    __syncthreads();
  }

  int col = (l & 15);
#pragma unroll
  for (int nt = 0; nt < 4; ++nt) {
#pragma unroll
    for (int j = 0; j < 4; ++j) {
      int r = 16 * w + (l >> 4) * 4 + j;
      size_t gr = row0 + r;
      if (MODE == 0)
        Y[gr * (NHEADS * 64) + head * 64 + 16 * nt + col] = acc[nt][j];
      else
        Y[gr * 64 + 16 * nt + col] = acc[nt][j];
    }
  }
  float aS[4], aD[4];
#pragma unroll
  for (int nt = 0; nt < 4; ++nt) {
    aS[nt] = av[16 * nt + col];
    aD[nt] = av[64 + 16 * nt + col];
  }
  float s1[4] = {0.f, 0.f, 0.f, 0.f}, s2[4] = {0.f, 0.f, 0.f, 0.f};
#pragma unroll
  for (int nt = 0; nt < 4; ++nt)
#pragma unroll
    for (int j = 0; j < 4; ++j) {
      s1[j] = fmaf(acc[nt][j], aS[nt], s1[j]);
      s2[j] = fmaf(acc[nt][j], aD[nt], s2[j]);
    }
#pragma unroll
  for (int off = 1; off < 16; off <<= 1) {
#pragma unroll
    for (int j = 0; j < 4; ++j) {
      s1[j] += __shfl_xor(s1[j], off);
      s2[j] += __shfl_xor(s2[j], off);
    }
  }
  if (col == 0) {
#pragma unroll
    for (int j = 0; j < 4; ++j) {
      int r = 16 * w + (l >> 4) * 4 + j;
      int gr = row0 + r;
      size_t si;
      if (MODE == 0) {
        int b = gr >> 11, n = gr & (N_ - 1);
        si = (size_t)(b * NHEADS + head) * N_ + n;
      } else {
        si = gr;
      }
      so_src[si] = s1[j];
      so_dst[si] = s2[j];
    }
  }
}

// ---------------------------------------------------------------------------
// Sparse attention aggregation: 16-deep then 8-deep software pipeline.
// RS = row stride of the feature plane.
// ---------------------------------------------------------------------------
template <int RS>
__device__ __forceinline__ float sparse_agg(
    const float* __restrict__ plane, const float* __restrict__ sdb,
    const int* __restrict__ nb, int dg, float ss, int lane) {
  float acc0 = 0.f, acc1 = 0.f, acc2 = 0.f, acc3 = 0.f;
  float den0 = 0.f, den1 = 0.f, den2 = 0.f, den3 = 0.f;
  int k = 0;
  for (; k + 16 <= dg; k += 16) {
    int m[16];
    float sv[16], hv[16];
#pragma unroll
    for (int j = 0; j < 16; ++j) m[j] = nb[k + j];
#pragma unroll
    for (int j = 0; j < 16; ++j) sv[j] = sdb[m[j]];
#pragma unroll
    for (int j = 0; j < 16; ++j) hv[j] = plane[(size_t)m[j] * RS + lane];
#pragma unroll
    for (int j = 0; j < 16; ++j) {
      float s = ss + sv[j];
      float lr = s > 0.f ? s : LRELU_ALPHA * s;
      float ev = __expf(-lr);
      switch (j & 3) {
        case 0: den0 += ev; acc0 = fmaf(ev, hv[j], acc0); break;
        case 1: den1 += ev; acc1 = fmaf(ev, hv[j], acc1); break;
        case 2: den2 += ev; acc2 = fmaf(ev, hv[j], acc2); break;
        default: den3 += ev; acc3 = fmaf(ev, hv[j], acc3); break;
      }
    }
  }
  for (; k + 8 <= dg; k += 8) {
    int m[8];
    float sv[8], hv[8];
#pragma unroll
    for (int j = 0; j < 8; ++j) m[j] = nb[k + j];
#pragma unroll
    for (int j = 0; j < 8; ++j) sv[j] = sdb[m[j]];
#pragma unroll
    for (int j = 0; j < 8; ++j) hv[j] = plane[(size_t)m[j] * RS + lane];
#pragma unroll
    for (int j = 0; j < 8; ++j) {
      float s = ss + sv[j];
      float lr = s > 0.f ? s : LRELU_ALPHA * s;
      float ev = __expf(-lr);
      if (j & 1) { den1 += ev; acc1 = fmaf(ev, hv[j], acc1); }
      else       { den0 += ev; acc0 = fmaf(ev, hv[j], acc0); }
    }
  }
  for (; k < dg; ++k) {
    int m = nb[k];
    float s = ss + sdb[m];
    float lr = s > 0.f ? s : LRELU_ALPHA * s;
    float ev = __expf(-lr);
    den0 += ev;
    acc0 = fmaf(ev, plane[(size_t)m * RS + lane], acc0);
  }
  return ((acc0 + acc1) + (acc2 + acc3)) / ((den0 + den1) + (den2 + den3));
}

// ---------------------------------------------------------------------------
// Layer-1 aggregation: one BLOCK per (b,n); 4 waves = 4 heads.
// ---------------------------------------------------------------------------
__global__ __launch_bounds__(256) void attn1_kernel(
    const float* __restrict__ Hm, const float* __restrict__ ssrc,
    const float* __restrict__ sdst, const int* __restrict__ nbr,
    const int* __restrict__ deg, unsigned short* __restrict__ h1h,
    unsigned short* __restrict__ h1l) {
  int bn = blockIdx.x;               // 0..B*N-1
  int n = bn & (N_ - 1), b = bn >> 11;
  int w = threadIdx.x >> 6;          // head
  int lane = threadIdx.x & 63;
  __shared__ int lds_nbr[MAXDEG];
  int dg = deg[n];
  for (int k = threadIdx.x; k < dg; k += 256) lds_nbr[k] = nbr[n * MAXDEG + k];
  __syncthreads();
  int bh = b * NHEADS + w;
  float ss = ssrc[(size_t)bh * N_ + n];
  const float* sdb = sdst + (size_t)bh * N_;
  const float* plane = Hm + (size_t)b * N_ * (NHEADS * 64) + w * 64;
  float o = sparse_agg<NHEADS * 64>(plane, sdb, lds_nbr, dg, ss, lane);
  o = o > 0.f ? o : expm1f(o);
  unsigned short hi = f2bf_rne(o);
  size_t oi = (size_t)bn * (NHEADS * NHID) + w * 64 + lane;
  h1h[oi] = hi;
  h1l[oi] = f2bf_rne(o - bf2f(hi));
}

// ---------------------------------------------------------------------------
// Layer-2 aggregation + final ELU -> d_out. One wave per (b,n).
// ---------------------------------------------------------------------------
__global__ __launch_bounds__(256) void attn2_kernel(
    const float* __restrict__ G, const float* __restrict__ tsrc,
    const float* __restrict__ tdst, const int* __restrict__ nbr,
    const int* __restrict__ deg, float* __restrict__ out) {
  int w = threadIdx.x >> 6, lane = threadIdx.x & 63;
  int gr = blockIdx.x * 4 + w;        // 0..B*N
  int n = gr & (N_ - 1);
  int b = gr >> 11;
  float o = sparse_agg<64>(G + (size_t)b * N_ * 64, tdst + (size_t)b * N_,
                           nbr + n * MAXDEG, deg[n], tsrc[gr], lane);
  out[(size_t)gr * 64 + lane] = o > 0.f ? o : expm1f(o);
}

// ---------------------------------------------------------------------------
extern "C" void kernel_launch(void* const* d_in, const int* in_sizes, int n_in,
                              void* d_out, int out_size, void* d_ws, size_t ws_size,
                              hipStream_t stream) {
  const float* x   = (const float*)d_in[0];   // [B,N,512]
  const float* adj = (const float*)d_in[1];   // [N,N]
  const float* W1  = (const float*)d_in[2];   // [H,512,64]
  const float* a1  = (const float*)d_in[3];   // [H,128]
  const float* W2  = (const float*)d_in[4];   // [256,64]
  const float* a2  = (const float*)d_in[5];   // [128]
  float* out = (float*)d_out;                 // [B,N,64] fp32

  char* ws = (char*)d_ws;
  float* h    = (float*)ws; ws += (size_t)B_ * N_ * 256 * 4;          // 8 MB [b,n,h*64]
  float* g    = (float*)ws; ws += (size_t)B_ * N_ * 64 * 4;           // 2 MB
  float* ssrc = (float*)ws; ws += (size_t)B_ * NHEADS * N_ * 4;
  float* sdst = (float*)ws; ws += (size_t)B_ * NHEADS * N_ * 4;
  float* tsrc = (float*)ws; ws += (size_t)B_ * N_ * 4;
  float* tdst = (float*)ws; ws += (size_t)B_ * N_ * 4;
  int*   nbr  = (int*)ws;   ws += (size_t)N_ * MAXDEG * 4;            // 1 MB
  int*   deg  = (int*)ws;   ws += (size_t)N_ * 4;
  ws = (char*)(((size_t)ws + 255) & ~(size_t)255);
  unsigned short* wt1h = (unsigned short*)ws; ws += (size_t)NHEADS * 64 * NFEAT * 2;
  unsigned short* wt1l = (unsigned short*)ws; ws += (size_t)NHEADS * 64 * NFEAT * 2;
  unsigned short* wt2h = (unsigned short*)ws; ws += (size_t)64 * 256 * 2;
  unsigned short* wt2l = (unsigned short*)ws; ws += (size_t)64 * 256 * 2;
  unsigned short* h1h  = (unsigned short*)ws; ws += (size_t)B_ * N_ * 256 * 2;   // 4.2 MB
  unsigned short* h1l  = (unsigned short*)ws; ws += (size_t)B_ * N_ * 256 * 2;   // 4.2 MB

  // prep: blocks [0,2048) adj | [2048,2080) W1 | [2080,2084) W2
  prep_kernel<<<N_ + 32 + 4, 256, 0, stream>>>(adj, nbr, deg, W1, wt1h, wt1l,
                                               W2, wt2h, wt2l);
  gemm_mfma_kernel<NFEAT, 0><<<B_ * N_ / 64 * NHEADS, 256, 0, stream>>>(
      x, nullptr, nullptr, wt1h, wt1l, a1, h, ssrc, sdst);
  attn1_kernel<<<B_ * N_, 256, 0, stream>>>(h, ssrc, sdst, nbr, deg, h1h, h1l);
  gemm_mfma_kernel<256, 1><<<B_ * N_ / 64, 256, 0, stream>>>(
      nullptr, h1h, h1l, wt2h, wt2l, a2, g, tsrc, tdst);
  attn2_kernel<<<B_ * N_ / 4, 256, 0, stream>>>(g, tsrc, tdst, nbr, deg, out);
}